// Round 11
// baseline (114.278 us; speedup 1.0000x reference)
//
#include <hip/hip_runtime.h>
#include <math.h>

#define NPOS  32768      // B*H*W
#define CDIM  128
#define HS    64
#define WSZ   64

typedef __bf16 bf8_t  __attribute__((ext_vector_type(8)));
typedef float  f32x4  __attribute__((ext_vector_type(4)));

__device__ __forceinline__ float gelu_exact(float x) {
    return 0.5f * x * (1.0f + erff(x * 0.70710678118654752f));
}

__device__ __forceinline__ unsigned short bf16c(float v) {
    return __builtin_bit_cast(unsigned short, (__bf16)v);
}

__device__ __forceinline__ uint4 pack8hi(const float* v) {
    unsigned hh[8];
    #pragma unroll
    for (int i = 0; i < 8; ++i) hh[i] = (unsigned)bf16c(v[i]);
    return make_uint4(hh[0] | (hh[1] << 16), hh[2] | (hh[3] << 16),
                      hh[4] | (hh[5] << 16), hh[6] | (hh[7] << 16));
}

__device__ __forceinline__ float bfd(unsigned u) {        // low 16 bits as bf16
    return __builtin_bit_cast(float, u << 16);
}

// unpack uint4 (8 bf16) and fma into acc[8] with weight
__device__ __forceinline__ void ufma(float* acc, uint4 c, float wgt) {
    const unsigned* cc = (const unsigned*)&c;
    #pragma unroll
    for (int j = 0; j < 4; ++j) {
        acc[2 * j]     += __builtin_bit_cast(float, cc[j] << 16) * wgt;
        acc[2 * j + 1] += __builtin_bit_cast(float, cc[j] & 0xFFFF0000u) * wgt;
    }
}

// ---------------------------------------------------------------------------
// A-frag layouts (K=KC*32):
//  hi/lo buffers: block(rt,kc) = 1024 ush (hi 512 | lo 512)
//  hi-only buffers: block(rt,kc) = 512 ush
//  elem: lane*8 + i, lane = (row%16) + ((k%32)/8)*16, i = k%8
// ---------------------------------------------------------------------------

// ---------------------------------------------------------------------------
// prep body: blocks [0,2048) aprep: inp -> hi-only frags
//            [2048,2178) border: zero 1-px ring of bf16 xpad
//            [2178,2232) wprep: weights -> frag bf16
// ---------------------------------------------------------------------------
__device__ void prep_body(
    int bid, int tid,
    const float* __restrict__ inp, unsigned short* __restrict__ inpf,
    unsigned short* __restrict__ xpad,
    const float* __restrict__ w0, const float* __restrict__ w1,
    const float* __restrict__ w2, const float* __restrict__ w3,
    const float* __restrict__ w4, unsigned short* __restrict__ wb)
{
    if (bid < 2048) {
        int idx = bid * 256 + tid;                  // 32768*16
        int r = idx >> 4, k8 = (idx & 15) * 8;
        float t[8];
        *(float4*)(t)     = *(const float4*)(inp + (size_t)r * 128 + k8);
        *(float4*)(t + 4) = *(const float4*)(inp + (size_t)r * 128 + k8 + 4);
        uint4 hi = pack8hi(t);
        int rt = r >> 4, kc = k8 >> 5, lp = (r & 15) + ((k8 & 31) >> 3) * 16;
        size_t base = ((size_t)rt * 4 + kc) * 512 + lp * 8;
        *(uint4*)(inpf + base) = hi;
    } else if (bid < 2178) {
        int idx = (bid - 2048) * 256 + tid;         // 2080 cells * 16
        if (idx < 33280) {
            int c8 = (idx & 15) * 8;
            int cell = idx >> 4;
            int b = cell / 260, r = cell % 260;
            int h, w;
            if (r < 66)       { h = 0;  w = r; }
            else if (r < 132) { h = 65; w = r - 66; }
            else { int rr = r - 132; h = 1 + (rr >> 1); w = (rr & 1) * 65; }
            size_t o = (((size_t)b * 66 + h) * 66 + w) * 128 + c8;
            *(uint4*)(xpad + o) = make_uint4(0u, 0u, 0u, 0u);
        }
    } else {
        int sub = (bid - 2178) * 4 + (tid >> 6);    // 0..215
        int lane = tid & 63;
        int NT, K, local; unsigned short* out; bool hl; bool comb = false;
        const float* W = nullptr; int N = 0;
        if (sub < 32)       { NT = 8;  K = 128; out = wb;          local = sub;       hl = false; W = w0; N = 128; }
        else if (sub < 88)  { NT = 14; K = 128; out = wb + 16384;  local = sub - 32;  hl = false; comb = true; }
        else if (sub < 152) { NT = 16; K = 128; out = wb + 45056;  local = sub - 88;  hl = true;  W = w3; N = 256; }
        else                { NT = 8;  K = 256; out = wb + 110592; local = sub - 152; hl = true;  W = w4; N = 128; }
        int KC = K / 32;
        int unit = KC * NT * 512;
        int kc = local / NT, t = local % NT;
        int nt = t * 16 + (lane & 15);
        const float* Wp = W; int n = nt, Nv = N;
        if (comb) {
            if (t < 9) { Wp = w1; n = nt;       Nv = 144; }
            else       { Wp = w2; n = nt - 144; Nv = 72;  }
        }
        int kb = kc * 32 + (lane >> 4) * 8;
        size_t base = ((size_t)local * 64 + lane) * 8;
        #pragma unroll
        for (int i = 0; i < 8; ++i) {
            float v = (n < Nv) ? Wp[(size_t)n * K + kb + i] : 0.f;
            __bf16 h = (__bf16)v;
            out[base + i] = __builtin_bit_cast(unsigned short, h);
            if (hl) {
                __bf16 l = (__bf16)(v - (float)h);
                out[unit + base + i] = __builtin_bit_cast(unsigned short, l);
            }
        }
    }
}

// ---------------------------------------------------------------------------
// dwconv body: depthwise 3x3 (NHWC) -> bf16 ydw + partial BN sums (fp32)
// ---------------------------------------------------------------------------
__device__ void dwconv_body(
    int blk, int tid,
    const float* __restrict__ inp, const float* __restrict__ dww,
    const float* __restrict__ dwb, unsigned short* __restrict__ ydwb,
    float* __restrict__ psum, float* __restrict__ psq)
{
    int b = blk >> 6, h = blk & 63;
    int c4 = (tid & 31) * 4;
    int wg = tid >> 5;               // 0..7

    float wreg[4][9];
    #pragma unroll
    for (int cc = 0; cc < 4; ++cc)
        #pragma unroll
        for (int p = 0; p < 9; ++p)
            wreg[cc][p] = dww[(c4 + cc) * 9 + p];
    float bia[4];
    #pragma unroll
    for (int cc = 0; cc < 4; ++cc) bia[cc] = dwb[c4 + cc];

    float s4[4] = {0,0,0,0}, q4[4] = {0,0,0,0};
    const float* ibase = inp + (size_t)(b << 12) * CDIM;

    for (int i = 0; i < 8; ++i) {
        int w = wg + i * 8;
        float acc[4] = {bia[0], bia[1], bia[2], bia[3]};
        #pragma unroll
        for (int ky = 0; ky < 3; ++ky) {
            int yy = h + ky - 1;
            if (yy < 0 || yy >= HS) continue;
            #pragma unroll
            for (int kx = 0; kx < 3; ++kx) {
                int xx = w + kx - 1;
                if (xx < 0 || xx >= WSZ) continue;
                float4 v = *(const float4*)(ibase + (size_t)(yy * 64 + xx) * CDIM + c4);
                int p = ky * 3 + kx;
                acc[0] += v.x * wreg[0][p];
                acc[1] += v.y * wreg[1][p];
                acc[2] += v.z * wreg[2][p];
                acc[3] += v.w * wreg[3][p];
            }
        }
        ushort4 o;
        o.x = bf16c(acc[0]); o.y = bf16c(acc[1]);
        o.z = bf16c(acc[2]); o.w = bf16c(acc[3]);
        *(ushort4*)(ydwb + ((size_t)(b << 12) + h * 64 + w) * CDIM + c4) = o;
        #pragma unroll
        for (int cc = 0; cc < 4; ++cc) { s4[cc] += acc[cc]; q4[cc] += acc[cc] * acc[cc]; }
    }

    __shared__ float ls[8][128], lq[8][128];
    #pragma unroll
    for (int cc = 0; cc < 4; ++cc) { ls[wg][c4 + cc] = s4[cc]; lq[wg][c4 + cc] = q4[cc]; }
    __syncthreads();
    if (tid < 128) {
        float s = 0.f, q = 0.f;
        #pragma unroll
        for (int r = 0; r < 8; ++r) { s += ls[r][tid]; q += lq[r][tid]; }
        psum[blk * 128 + tid] = s;
        psq [blk * 128 + tid] = q;
    }
}

// K_pd: merged prep (2232 blocks) + dwconv (512 blocks). grid 2744.
__global__ __launch_bounds__(256) void k_pd(
    const float* __restrict__ inp, unsigned short* __restrict__ inpf,
    unsigned short* __restrict__ xpad,
    const float* __restrict__ w0, const float* __restrict__ w1,
    const float* __restrict__ w2, const float* __restrict__ w3,
    const float* __restrict__ w4, unsigned short* __restrict__ wb,
    const float* __restrict__ dww, const float* __restrict__ dwb,
    unsigned short* __restrict__ ydwb, float* __restrict__ psum,
    float* __restrict__ psq)
{
    int bid = blockIdx.x;
    if (bid < 2232) prep_body(bid, threadIdx.x, inp, inpf, xpad, w0, w1, w2, w3, w4, wb);
    else            dwconv_body(bid - 2232, threadIdx.x, inp, dww, dwb, ydwb, psum, psq);
}

// ---------------------------------------------------------------------------
// K2: finalize BN stats -> scale/shift per channel.
// ---------------------------------------------------------------------------
__global__ __launch_bounds__(256) void k_bnstats(
    const float* __restrict__ psum, const float* __restrict__ psq,
    const float* __restrict__ gamma, const float* __restrict__ beta,
    float* __restrict__ sc, float* __restrict__ sh)
{
    int c = blockIdx.x;
    int t = threadIdx.x;
    float s = psum[t * 128 + c] + psum[(t + 256) * 128 + c];
    float q = psq [t * 128 + c] + psq [(t + 256) * 128 + c];
    __shared__ float rs[256], rq[256];
    rs[t] = s; rq[t] = q; __syncthreads();
    for (int off = 128; off > 0; off >>= 1) {
        if (t < off) { rs[t] += rs[t + off]; rq[t] += rq[t + off]; }
        __syncthreads();
    }
    if (t == 0) {
        float mean = rs[0] * (1.0f / 32768.0f);
        float var  = rq[0] * (1.0f / 32768.0f) - mean * mean;
        float scale = gamma[c] * rsqrtf(var + 1e-5f);
        sc[c] = scale;
        sh[c] = beta[c] - mean * scale;
    }
}

// ---------------------------------------------------------------------------
// bngelu body: bf16 ydw -> BN + exact GELU -> x1 hi-only frags.
// ---------------------------------------------------------------------------
__device__ void bngelu_body(
    int bid, int tid,
    const unsigned short* __restrict__ ydwb, const float* __restrict__ sc,
    const float* __restrict__ sh, unsigned short* __restrict__ dst)
{
    int idx = bid * 256 + tid;   // 32768*16
    int r = idx >> 4, k8 = (idx & 15) * 8;
    uint4 yv = *(const uint4*)(ydwb + (size_t)r * 128 + k8);
    const unsigned* cc = (const unsigned*)&yv;
    float t[8];
    #pragma unroll
    for (int j = 0; j < 4; ++j) {
        t[2 * j]     = bfd(cc[j]);
        t[2 * j + 1] = __builtin_bit_cast(float, cc[j] & 0xFFFF0000u);
    }
    float s[8], h[8];
    *(float4*)(s)     = *(const float4*)(sc + k8);
    *(float4*)(s + 4) = *(const float4*)(sc + k8 + 4);
    *(float4*)(h)     = *(const float4*)(sh + k8);
    *(float4*)(h + 4) = *(const float4*)(sh + k8 + 4);
    #pragma unroll
    for (int i = 0; i < 8; ++i) t[i] = gelu_exact(t[i] * s[i] + h[i]);
    uint4 hi = pack8hi(t);
    int rt = r >> 4, kc = k8 >> 5, lp = (r & 15) + ((k8 & 31) >> 3) * 16;
    size_t base = ((size_t)rt * 4 + kc) * 512 + lp * 8;
    *(uint4*)(dst + base) = hi;
}

// ---------------------------------------------------------------------------
// Frag-stream MFMA GEMM body.
// ALO/WLO: whether A / W carry a lo (bf16 residual) stream.
// MODE 0: fp32 row-major + bias. MODE 3: bf16 padded [b][66][66][128].
// MODE 4: bf16 split store: tiles 0..8 -> offs (ld 144), 9..13 -> msk (ld 72).
// ---------------------------------------------------------------------------
template<int KDIM, int NT_TOT, int NT_W, int MODE, int NV, int ALO, int WLO>
__device__ void fgemm_body(
    int bx, int by, int tid,
    const unsigned short* __restrict__ AF, const unsigned short* __restrict__ WF,
    const float* __restrict__ bias, float* __restrict__ C, int ldc,
    unsigned short* __restrict__ OF, const float* __restrict__ bias2,
    float* __restrict__ C2)
{
    constexpr int KC = KDIM / 32;
    constexpr int ABLK = ALO ? 128 : 64;   // bf8 units per (rt,kc) block
    int lane = tid & 63, w = tid >> 6;
    int rt0 = bx * 8 + w * 2;      // 2 rowtiles per wave
    int t0 = by * NT_W;            // n-tile chunk base

    f32x4 acc[2][NT_W];
    #pragma unroll
    for (int rt = 0; rt < 2; ++rt)
        #pragma unroll
        for (int t = 0; t < NT_W; ++t) acc[rt][t] = (f32x4){0.f, 0.f, 0.f, 0.f};

    const bf8_t* Ab0 = (const bf8_t*)AF + (size_t)rt0 * KC * ABLK + lane;
    const bf8_t* Ab1 = Ab0 + KC * ABLK;
    const bf8_t* WHp = (const bf8_t*)WF + lane;
    const bf8_t* WLp = WHp + KC * NT_TOT * 64;

    #pragma unroll
    for (int kc = 0; kc < KC; ++kc) {
        bf8_t a0h = Ab0[kc * ABLK];
        bf8_t a1h = Ab1[kc * ABLK];
        bf8_t a0l, a1l;
        if (ALO) { a0l = Ab0[kc * ABLK + 64]; a1l = Ab1[kc * ABLK + 64]; }
        #pragma unroll
        for (int t = 0; t < NT_W; ++t) {
            int tg = t0 + t;
            if (tg < NT_TOT) {
                bf8_t wh = WHp[(kc * NT_TOT + tg) * 64];
                acc[0][t] = __builtin_amdgcn_mfma_f32_16x16x32_bf16(wh, a0h, acc[0][t], 0, 0, 0);
                acc[1][t] = __builtin_amdgcn_mfma_f32_16x16x32_bf16(wh, a1h, acc[1][t], 0, 0, 0);
                if (WLO) {
                    bf8_t wl = WLp[(kc * NT_TOT + tg) * 64];
                    acc[0][t] = __builtin_amdgcn_mfma_f32_16x16x32_bf16(wl, a0h, acc[0][t], 0, 0, 0);
                    acc[1][t] = __builtin_amdgcn_mfma_f32_16x16x32_bf16(wl, a1h, acc[1][t], 0, 0, 0);
                }
                if (ALO) {
                    acc[0][t] = __builtin_amdgcn_mfma_f32_16x16x32_bf16(wh, a0l, acc[0][t], 0, 0, 0);
                    acc[1][t] = __builtin_amdgcn_mfma_f32_16x16x32_bf16(wh, a1l, acc[1][t], 0, 0, 0);
                }
            }
        }
    }

    #pragma unroll
    for (int rt = 0; rt < 2; ++rt) {
        if (MODE == 0) {
            int m = (rt0 + rt) * 16 + (lane & 15);
            #pragma unroll
            for (int t = 0; t < NT_W; ++t) {
                int tg = t0 + t;
                int nb = tg * 16 + ((lane >> 4) << 2);
                if (tg < NT_TOT && nb + 4 <= NV) {
                    float4 bb = *(const float4*)(bias + nb);
                    f32x4 a = acc[rt][t];
                    float4 v = {a[0] + bb.x, a[1] + bb.y, a[2] + bb.z, a[3] + bb.w};
                    *(float4*)(C + (size_t)m * ldc + nb) = v;
                }
            }
        } else if (MODE == 3) {
            // bf16 store into zero-padded [b][66][66][128]
            unsigned short* Cp = (unsigned short*)C;
            int m = (rt0 + rt) * 16 + (lane & 15);
            int bb_ = m >> 12, hwm = m & 4095;
            size_t rowb = (((size_t)bb_ * 66 + (hwm >> 6) + 1) * 66 + (hwm & 63) + 1) * 128;
            #pragma unroll
            for (int t = 0; t < NT_W; ++t) {
                int tg = t0 + t;
                int nb = tg * 16 + ((lane >> 4) << 2);
                if (tg < NT_TOT) {
                    float4 bb = *(const float4*)(bias + nb);
                    f32x4 a = acc[rt][t];
                    ushort4 v;
                    v.x = bf16c(a[0] + bb.x); v.y = bf16c(a[1] + bb.y);
                    v.z = bf16c(a[2] + bb.z); v.w = bf16c(a[3] + bb.w);
                    *(ushort4*)(Cp + rowb + nb) = v;
                }
            }
        } else if (MODE == 4) {
            // bf16 split store: offs (C, ld 144) and msk (C2, ld 72)
            unsigned short* Co = (unsigned short*)C;
            unsigned short* Cm = (unsigned short*)C2;
            int m = (rt0 + rt) * 16 + (lane & 15);
            #pragma unroll
            for (int t = 0; t < NT_W; ++t) {
                int tg = t0 + t;
                if (tg < NT_TOT) {
                    int nb = tg * 16 + ((lane >> 4) << 2);
                    f32x4 a = acc[rt][t];
                    if (nb < 144) {
                        float4 bb = *(const float4*)(bias + nb);
                        ushort4 v;
                        v.x = bf16c(a[0] + bb.x); v.y = bf16c(a[1] + bb.y);
                        v.z = bf16c(a[2] + bb.z); v.w = bf16c(a[3] + bb.w);
                        *(ushort4*)(Co + (size_t)m * 144 + nb) = v;
                    } else {
                        int col = nb - 144;
                        if (col + 4 <= 72) {
                            float4 bb = *(const float4*)(bias2 + col);
                            ushort4 v;
                            v.x = bf16c(a[0] + bb.x); v.y = bf16c(a[1] + bb.y);
                            v.z = bf16c(a[2] + bb.z); v.w = bf16c(a[3] + bb.w);
                            *(ushort4*)(Cm + (size_t)m * 72 + col) = v;
                        }
                    }
                }
            }
        }
    }
}

template<int KDIM, int NT_TOT, int NT_W, int MODE, int NV, int ALO, int WLO>
__global__ __launch_bounds__(256) void k_fgemm(
    const unsigned short* __restrict__ AF, const unsigned short* __restrict__ WF,
    const float* __restrict__ bias, float* __restrict__ C, int ldc,
    unsigned short* __restrict__ OF, const float* __restrict__ bias2,
    float* __restrict__ C2)
{
    fgemm_body<KDIM, NT_TOT, NT_W, MODE, NV, ALO, WLO>(
        blockIdx.x, blockIdx.y, threadIdx.x, AF, WF, bias, C, ldc, OF, bias2, C2);
}

// K_bp: merged bngelu (2048 blocks) + proj GEMM (1024 blocks). grid 3072.
__global__ __launch_bounds__(256) void k_bp(
    const unsigned short* __restrict__ ydwb, const float* __restrict__ sc,
    const float* __restrict__ sh, unsigned short* __restrict__ x1f,
    const unsigned short* __restrict__ inpf, const unsigned short* __restrict__ wprojf,
    const float* __restrict__ bproj, unsigned short* __restrict__ xpad)
{
    int bid = blockIdx.x;
    if (bid < 2048) {
        bngelu_body(bid, threadIdx.x, ydwb, sc, sh, x1f);
    } else {
        int pbid = bid - 2048;
        fgemm_body<128, 8, 2, 3, 128, 0, 0>(pbid & 255, pbid >> 8, threadIdx.x,
            inpf, wprojf, bproj, (float*)xpad, 0, nullptr, nullptr, nullptr);
    }
}

// ---------------------------------------------------------------------------
// K6: DCNv3 core. thread = (pos, g), 16 channels. grid 1024, block 256.
// bf16 xpad gathers, bf16 offs/msk inputs, clamped addressing.
// Softmax once per (pos,g). Output packed as fc1 hi-only A-frags.
// ---------------------------------------------------------------------------
__global__ __launch_bounds__(256) void k_dcn(
    const unsigned short* __restrict__ xpad, const unsigned short* __restrict__ offs,
    const unsigned short* __restrict__ msk, unsigned short* __restrict__ dcnf)
{
    int u = blockIdx.x * 256 + threadIdx.x;  // 32768*8
    int g = u & 7;
    int pos = u >> 3;
    int b = pos >> 12, hw = pos & 4095, h = hw >> 6, w = hw & 63;

    const unsigned short* ml = msk + (size_t)pos * 72 + g * 9;
    float e[9];
    float mx = -1e30f;
    #pragma unroll
    for (int p = 0; p < 9; ++p) { e[p] = bfd((unsigned)ml[p]); mx = fmaxf(mx, e[p]); }
    float ssum = 0.f;
    #pragma unroll
    for (int p = 0; p < 9; ++p) { e[p] = __expf(e[p] - mx); ssum += e[p]; }
    float inv = 1.0f / ssum;

    const unsigned short* ob = offs + (size_t)pos * 144 + g * 18;
    const unsigned short* xb = xpad + (size_t)b * 557568 + g * 16;  // 66*66*128/b

    float acc[16];
    #pragma unroll
    for (int i = 0; i < 16; ++i) acc[i] = 0.f;

    #pragma unroll
    for (int p = 0; p < 9; ++p) {
        unsigned dpair = *(const unsigned*)(ob + p * 2);
        float dx = bfd(dpair);
        float dy = __builtin_bit_cast(float, dpair & 0xFFFF0000u);
        float px = (float)(w + (p % 3)) + dx;   // padded-grid coords
        float py = (float)(h + (p / 3)) + dy;
        float x0f = floorf(px), y0f = floorf(py);
        float wx = px - x0f, wy = py - y0f;
        int ix = (int)x0f, iy = (int)y0f;
        int ix0 = max(min(ix, 65), 0),     ix1 = max(min(ix + 1, 65), 0);
        int iy0 = max(min(iy, 65), 0),     iy1 = max(min(iy + 1, 65), 0);
        int r0 = iy0 * 66, r1 = iy1 * 66;

        float mp  = e[p] * inv;
        float w11 = wy * wx * mp;
        float w10 = wy * mp - w11;
        float w01 = wx * mp - w11;
        float w00 = mp - w01 - w10 - w11;

        const unsigned short* c00 = xb + (size_t)(r0 + ix0) * 128;
        const unsigned short* c01 = xb + (size_t)(r0 + ix1) * 128;
        const unsigned short* c10 = xb + (size_t)(r1 + ix0) * 128;
        const unsigned short* c11 = xb + (size_t)(r1 + ix1) * 128;

        uint4 a00 = *(const uint4*)(c00), b00 = *(const uint4*)(c00 + 8);
        uint4 a01 = *(const uint4*)(c01), b01 = *(const uint4*)(c01 + 8);
        uint4 a10 = *(const uint4*)(c10), b10 = *(const uint4*)(c10 + 8);
        uint4 a11 = *(const uint4*)(c11), b11 = *(const uint4*)(c11 + 8);

        ufma(acc,     a00, w00); ufma(acc + 8, b00, w00);
        ufma(acc,     a01, w01); ufma(acc + 8, b01, w01);
        ufma(acc,     a10, w10); ufma(acc + 8, b10, w10);
        ufma(acc,     a11, w11); ufma(acc + 8, b11, w11);
    }

    // pack 16 channels as two hi-only frag groups
    int rt = pos >> 4, kc = g >> 1;
    int lp0 = (pos & 15) + (g & 1) * 32;
    size_t fb = ((size_t)rt * 4 + kc) * 512 + (size_t)lp0 * 8;
    uint4 hiA = pack8hi(acc);
    uint4 hiB = pack8hi(acc + 8);
    *(uint4*)(dcnf + fb)       = hiA;
    *(uint4*)(dcnf + fb + 128) = hiB;   // lp0+16
}

// ---------------------------------------------------------------------------
// K7: fused output MLP. wave = 1 rowtile (16 rows). grid 512, block 256.
// fc1 (A=dcnf hi-only, W hi/lo, swapped) -> GELU -> bf16 hidden in private
// per-wave LDS [16][264] -> fc2 A-frags from LDS (unswapped, W hi/lo) ->
// fp32 NCHW store. No barriers (wave-private LDS).
// ---------------------------------------------------------------------------
__global__ __launch_bounds__(256) void k_mlp(
    const unsigned short* __restrict__ dcnf, const unsigned short* __restrict__ wf1,
    const float* __restrict__ bfc1, const unsigned short* __restrict__ wf2,
    const float* __restrict__ bfc2, float* __restrict__ out)
{
    __shared__ unsigned short hid[4][16][264];   // 33 KB, +8 pad breaks bank stride
    int tid = threadIdx.x;
    int lane = tid & 63, w = tid >> 6;
    int rt = blockIdx.x * 4 + w;                 // rowtile 0..2047
    int m = lane & 15, hi4 = (lane >> 4) << 2;

    // ---- fc1 ----
    f32x4 acc[16];
    #pragma unroll
    for (int t = 0; t < 16; ++t) acc[t] = (f32x4){0.f, 0.f, 0.f, 0.f};
    const bf8_t* Ab  = (const bf8_t*)dcnf + (size_t)rt * 4 * 64 + lane;  // KC=4 hi-only
    const bf8_t* WH1 = (const bf8_t*)wf1 + lane;
    const bf8_t* WL1 = WH1 + 4 * 16 * 64;
    #pragma unroll
    for (int kc = 0; kc < 4; ++kc) {
        bf8_t ah = Ab[kc * 64];
        #pragma unroll
        for (int t = 0; t < 16; ++t) {
            bf8_t wh = WH1[(kc * 16 + t) * 64];
            bf8_t wl = WL1[(kc * 16 + t) * 64];
            acc[t] = __builtin_amdgcn_mfma_f32_16x16x32_bf16(wh, ah, acc[t], 0, 0, 0);
            acc[t] = __builtin_amdgcn_mfma_f32_16x16x32_bf16(wl, ah, acc[t], 0, 0, 0);
        }
    }
    // GELU + bf16 -> wave-private LDS (lane holds m = lane&15, n = t*16+hi4..+3)
    #pragma unroll
    for (int t = 0; t < 16; ++t) {
        int nb = t * 16 + hi4;
        float4 bb = *(const float4*)(bfc1 + nb);
        ushort4 v;
        v.x = bf16c(gelu_exact(acc[t][0] + bb.x));
        v.y = bf16c(gelu_exact(acc[t][1] + bb.y));
        v.z = bf16c(gelu_exact(acc[t][2] + bb.z));
        v.w = bf16c(gelu_exact(acc[t][3] + bb.w));
        *(ushort4*)(&hid[w][m][nb]) = v;
    }

    // ---- fc2 (reads only this wave's LDS region; no barrier needed) ----
    f32x4 acc2[8];
    #pragma unroll
    for (int t = 0; t < 8; ++t) acc2[t] = (f32x4){0.f, 0.f, 0.f, 0.f};
    const bf8_t* WH2 = (const bf8_t*)wf2 + lane;
    const bf8_t* WL2 = WH2 + 8 * 8 * 64;
    #pragma unroll
    for (int kc = 0; kc < 8; ++kc) {
        // standard A-frag from LDS: row = lane&15, k8 = kc*32 + (lane>>4)*8
        bf8_t ah = *(const bf8_t*)(&hid[w][m][kc * 32 + (lane >> 4) * 8]);
        #pragma unroll
        for (int t = 0; t < 8; ++t) {
            bf8_t wh = WH2[(kc * 8 + t) * 64];
            bf8_t wl = WL2[(kc * 8 + t) * 64];
            acc2[t] = __builtin_amdgcn_mfma_f32_16x16x32_bf16(ah, wh, acc2[t], 0, 0, 0);
            acc2[t] = __builtin_amdgcn_mfma_f32_16x16x32_bf16(ah, wl, acc2[t], 0, 0, 0);
        }
    }
    // NCHW transposed fp32 store: lane holds m4 = rt*16+hi4(+j), n = t*16+m
    int m4 = rt * 16 + hi4;
    int b = m4 >> 12, hw = m4 & 4095;
    #pragma unroll
    for (int t = 0; t < 8; ++t) {
        int n = t * 16 + m;
        float bb = bfc2[n];
        f32x4 a = acc2[t];
        float4 v = {a[0] + bb, a[1] + bb, a[2] + bb, a[3] + bb};
        *(float4*)(out + (((size_t)(b * 128 + n)) << 12) + hw) = v;
    }
}

// ---------------------------------------------------------------------------
extern "C" void kernel_launch(void* const* d_in, const int* in_sizes, int n_in,
                              void* d_out, int out_size, void* d_ws, size_t ws_size,
                              hipStream_t stream)
{
    const float* inp   = (const float*)d_in[0];
    const float* wproj = (const float*)d_in[1];
    const float* bproj = (const float*)d_in[2];
    const float* dww   = (const float*)d_in[3];
    const float* dwb   = (const float*)d_in[4];
    const float* gamma = (const float*)d_in[5];
    const float* beta  = (const float*)d_in[6];
    const float* woff  = (const float*)d_in[7];
    const float* boff  = (const float*)d_in[8];
    const float* wmask = (const float*)d_in[9];
    const float* bmask = (const float*)d_in[10];
    const float* wfc1  = (const float*)d_in[11];
    const float* bfc1  = (const float*)d_in[12];
    const float* wfc2  = (const float*)d_in[13];
    const float* bfc2  = (const float*)d_in[14];
    float* out = (float*)d_out;
    float* ws  = (float*)d_ws;

    // Region P: xpad (bf16) + offs (bf16)
    unsigned short* xpad = (unsigned short*)ws;              // 4,460,544 ush [proj..dcn]
    unsigned short* offs = (unsigned short*)(ws + 2230272);  // 4,718,592 ush [offmask..dcn]
    // Region A at ws+9179136: inpf [pd..bp-proj], dcnf [dcn..mlp]
    unsigned short* inpf  = (unsigned short*)(ws + 9179136);   // 4,194,304 ush hi-only
    unsigned short* dcnf  = (unsigned short*)(ws + 9179136);   // 4,194,304 ush hi-only
    unsigned short* x1f   = (unsigned short*)(ws + 13373440);  // 4,194,304 ush hi-only [bp..offmask]
    unsigned short* ydwb  = (unsigned short*)(ws + 15470592);  // 4,194,304 ush bf16 [pd..bp]
    // Rest
    unsigned short* msk = (unsigned short*)(ws + 17567744);  // 2,359,296 ush
    float* psum = ws + 19927040;                         // 65,536 f
    float* psq  = ws + 19992576;                         // 65,536 f
    float* scs  = ws + 20058112;                         // 128 f
    float* shs  = ws + 20058240;                         // 128 f
    unsigned short* wfr = (unsigned short*)(ws + 20058368);  // 176,128 ush

    unsigned short* wproj_f = wfr;            // hi-only, 16384
    unsigned short* womb_f  = wfr + 16384;    // hi-only combined, 28672
    unsigned short* wfc1_f  = wfr + 45056;    // hi/lo, 65536
    unsigned short* wfc2_f  = wfr + 110592;   // hi/lo, 65536

    k_pd<<<2744, 256, 0, stream>>>(inp, inpf, xpad, wproj, woff, wmask, wfc1, wfc2,
                                   wfr, dww, dwb, ydwb, psum, psq);
    k_bnstats<<<128, 256, 0, stream>>>(psum, psq, gamma, beta, scs, shs);
    k_bp<<<3072, 256, 0, stream>>>(ydwb, scs, shs, x1f, inpf, wproj_f, bproj, xpad);
    k_fgemm<128, 14, 4, 4, 224, 0, 0><<<dim3(256, 4), 256, 0, stream>>>(x1f, womb_f, boff, (float*)offs, 144, nullptr, bmask, (float*)msk);
    k_dcn<<<1024, 256, 0, stream>>>(xpad, offs, msk, dcnf);
    k_mlp<<<512, 256, 0, stream>>>(dcnf, wfc1_f, bfc1, wfc2_f, bfc2, out);
}

// Round 12
// 105.280 us; speedup vs baseline: 1.0855x; 1.0855x over previous
//
#include <hip/hip_runtime.h>
#include <math.h>

#define NPOS  32768      // B*H*W
#define CDIM  128
#define HS    64
#define WSZ   64

typedef __bf16 bf8_t  __attribute__((ext_vector_type(8)));
typedef float  f32x4  __attribute__((ext_vector_type(4)));

__device__ __forceinline__ float gelu_exact(float x) {
    return 0.5f * x * (1.0f + erff(x * 0.70710678118654752f));
}

__device__ __forceinline__ unsigned short bf16c(float v) {
    return __builtin_bit_cast(unsigned short, (__bf16)v);
}

__device__ __forceinline__ uint4 pack8hi(const float* v) {
    unsigned hh[8];
    #pragma unroll
    for (int i = 0; i < 8; ++i) hh[i] = (unsigned)bf16c(v[i]);
    return make_uint4(hh[0] | (hh[1] << 16), hh[2] | (hh[3] << 16),
                      hh[4] | (hh[5] << 16), hh[6] | (hh[7] << 16));
}

__device__ __forceinline__ float bfd(unsigned u) {        // low 16 bits as bf16
    return __builtin_bit_cast(float, u << 16);
}

// unpack uint4 (8 bf16) and fma into acc[8] with weight
__device__ __forceinline__ void ufma(float* acc, uint4 c, float wgt) {
    const unsigned* cc = (const unsigned*)&c;
    #pragma unroll
    for (int j = 0; j < 4; ++j) {
        acc[2 * j]     += __builtin_bit_cast(float, cc[j] << 16) * wgt;
        acc[2 * j + 1] += __builtin_bit_cast(float, cc[j] & 0xFFFF0000u) * wgt;
    }
}

// ---------------------------------------------------------------------------
// A-frag layouts (K=KC*32):
//  hi/lo buffers: block(rt,kc) = 1024 ush (hi 512 | lo 512)
//  hi-only buffers: block(rt,kc) = 512 ush
//  elem: lane*8 + i, lane = (row%16) + ((k%32)/8)*16, i = k%8
// ---------------------------------------------------------------------------

// ---------------------------------------------------------------------------
// prep body: blocks [0,2048) aprep: inp -> hi-only frags
//            [2048,2178) border: zero 1-px ring of bf16 xpad
//            [2178,2232) wprep: weights -> frag bf16
// ---------------------------------------------------------------------------
__device__ void prep_body(
    int bid, int tid,
    const float* __restrict__ inp, unsigned short* __restrict__ inpf,
    unsigned short* __restrict__ xpad,
    const float* __restrict__ w0, const float* __restrict__ w1,
    const float* __restrict__ w2, const float* __restrict__ w3,
    const float* __restrict__ w4, unsigned short* __restrict__ wb)
{
    if (bid < 2048) {
        int idx = bid * 256 + tid;                  // 32768*16
        int r = idx >> 4, k8 = (idx & 15) * 8;
        float t[8];
        *(float4*)(t)     = *(const float4*)(inp + (size_t)r * 128 + k8);
        *(float4*)(t + 4) = *(const float4*)(inp + (size_t)r * 128 + k8 + 4);
        uint4 hi = pack8hi(t);
        int rt = r >> 4, kc = k8 >> 5, lp = (r & 15) + ((k8 & 31) >> 3) * 16;
        size_t base = ((size_t)rt * 4 + kc) * 512 + lp * 8;
        *(uint4*)(inpf + base) = hi;
    } else if (bid < 2178) {
        int idx = (bid - 2048) * 256 + tid;         // 2080 cells * 16
        if (idx < 33280) {
            int c8 = (idx & 15) * 8;
            int cell = idx >> 4;
            int b = cell / 260, r = cell % 260;
            int h, w;
            if (r < 66)       { h = 0;  w = r; }
            else if (r < 132) { h = 65; w = r - 66; }
            else { int rr = r - 132; h = 1 + (rr >> 1); w = (rr & 1) * 65; }
            size_t o = (((size_t)b * 66 + h) * 66 + w) * 128 + c8;
            *(uint4*)(xpad + o) = make_uint4(0u, 0u, 0u, 0u);
        }
    } else {
        int sub = (bid - 2178) * 4 + (tid >> 6);    // 0..215
        int lane = tid & 63;
        int NT, K, local; unsigned short* out; bool hl; bool comb = false;
        const float* W = nullptr; int N = 0;
        if (sub < 32)       { NT = 8;  K = 128; out = wb;          local = sub;       hl = false; W = w0; N = 128; }
        else if (sub < 88)  { NT = 14; K = 128; out = wb + 16384;  local = sub - 32;  hl = false; comb = true; }
        else if (sub < 152) { NT = 16; K = 128; out = wb + 45056;  local = sub - 88;  hl = true;  W = w3; N = 256; }
        else                { NT = 8;  K = 256; out = wb + 110592; local = sub - 152; hl = true;  W = w4; N = 128; }
        int KC = K / 32;
        int unit = KC * NT * 512;
        int kc = local / NT, t = local % NT;
        int nt = t * 16 + (lane & 15);
        const float* Wp = W; int n = nt, Nv = N;
        if (comb) {
            if (t < 9) { Wp = w1; n = nt;       Nv = 144; }
            else       { Wp = w2; n = nt - 144; Nv = 72;  }
        }
        int kb = kc * 32 + (lane >> 4) * 8;
        size_t base = ((size_t)local * 64 + lane) * 8;
        #pragma unroll
        for (int i = 0; i < 8; ++i) {
            float v = (n < Nv) ? Wp[(size_t)n * K + kb + i] : 0.f;
            __bf16 h = (__bf16)v;
            out[base + i] = __builtin_bit_cast(unsigned short, h);
            if (hl) {
                __bf16 l = (__bf16)(v - (float)h);
                out[unit + base + i] = __builtin_bit_cast(unsigned short, l);
            }
        }
    }
}

// ---------------------------------------------------------------------------
// dwconv body: depthwise 3x3 (NHWC) -> bf16 ydw + partial BN sums (fp32)
// ---------------------------------------------------------------------------
__device__ void dwconv_body(
    int blk, int tid,
    const float* __restrict__ inp, const float* __restrict__ dww,
    const float* __restrict__ dwb, unsigned short* __restrict__ ydwb,
    float* __restrict__ psum, float* __restrict__ psq)
{
    int b = blk >> 6, h = blk & 63;
    int c4 = (tid & 31) * 4;
    int wg = tid >> 5;               // 0..7

    float wreg[4][9];
    #pragma unroll
    for (int cc = 0; cc < 4; ++cc)
        #pragma unroll
        for (int p = 0; p < 9; ++p)
            wreg[cc][p] = dww[(c4 + cc) * 9 + p];
    float bia[4];
    #pragma unroll
    for (int cc = 0; cc < 4; ++cc) bia[cc] = dwb[c4 + cc];

    float s4[4] = {0,0,0,0}, q4[4] = {0,0,0,0};
    const float* ibase = inp + (size_t)(b << 12) * CDIM;

    for (int i = 0; i < 8; ++i) {
        int w = wg + i * 8;
        float acc[4] = {bia[0], bia[1], bia[2], bia[3]};
        #pragma unroll
        for (int ky = 0; ky < 3; ++ky) {
            int yy = h + ky - 1;
            if (yy < 0 || yy >= HS) continue;
            #pragma unroll
            for (int kx = 0; kx < 3; ++kx) {
                int xx = w + kx - 1;
                if (xx < 0 || xx >= WSZ) continue;
                float4 v = *(const float4*)(ibase + (size_t)(yy * 64 + xx) * CDIM + c4);
                int p = ky * 3 + kx;
                acc[0] += v.x * wreg[0][p];
                acc[1] += v.y * wreg[1][p];
                acc[2] += v.z * wreg[2][p];
                acc[3] += v.w * wreg[3][p];
            }
        }
        ushort4 o;
        o.x = bf16c(acc[0]); o.y = bf16c(acc[1]);
        o.z = bf16c(acc[2]); o.w = bf16c(acc[3]);
        *(ushort4*)(ydwb + ((size_t)(b << 12) + h * 64 + w) * CDIM + c4) = o;
        #pragma unroll
        for (int cc = 0; cc < 4; ++cc) { s4[cc] += acc[cc]; q4[cc] += acc[cc] * acc[cc]; }
    }

    __shared__ float ls[8][128], lq[8][128];
    #pragma unroll
    for (int cc = 0; cc < 4; ++cc) { ls[wg][c4 + cc] = s4[cc]; lq[wg][c4 + cc] = q4[cc]; }
    __syncthreads();
    if (tid < 128) {
        float s = 0.f, q = 0.f;
        #pragma unroll
        for (int r = 0; r < 8; ++r) { s += ls[r][tid]; q += lq[r][tid]; }
        psum[blk * 128 + tid] = s;
        psq [blk * 128 + tid] = q;
    }
}

// K_pd: merged prep (2232 blocks) + dwconv (512 blocks). grid 2744.
__global__ __launch_bounds__(256) void k_pd(
    const float* __restrict__ inp, unsigned short* __restrict__ inpf,
    unsigned short* __restrict__ xpad,
    const float* __restrict__ w0, const float* __restrict__ w1,
    const float* __restrict__ w2, const float* __restrict__ w3,
    const float* __restrict__ w4, unsigned short* __restrict__ wb,
    const float* __restrict__ dww, const float* __restrict__ dwb,
    unsigned short* __restrict__ ydwb, float* __restrict__ psum,
    float* __restrict__ psq)
{
    int bid = blockIdx.x;
    if (bid < 2232) prep_body(bid, threadIdx.x, inp, inpf, xpad, w0, w1, w2, w3, w4, wb);
    else            dwconv_body(bid - 2232, threadIdx.x, inp, dww, dwb, ydwb, psum, psq);
}

// ---------------------------------------------------------------------------
// K2: finalize BN stats -> scale/shift per channel.
// ---------------------------------------------------------------------------
__global__ __launch_bounds__(256) void k_bnstats(
    const float* __restrict__ psum, const float* __restrict__ psq,
    const float* __restrict__ gamma, const float* __restrict__ beta,
    float* __restrict__ sc, float* __restrict__ sh)
{
    int c = blockIdx.x;
    int t = threadIdx.x;
    float s = psum[t * 128 + c] + psum[(t + 256) * 128 + c];
    float q = psq [t * 128 + c] + psq [(t + 256) * 128 + c];
    __shared__ float rs[256], rq[256];
    rs[t] = s; rq[t] = q; __syncthreads();
    for (int off = 128; off > 0; off >>= 1) {
        if (t < off) { rs[t] += rs[t + off]; rq[t] += rq[t + off]; }
        __syncthreads();
    }
    if (t == 0) {
        float mean = rs[0] * (1.0f / 32768.0f);
        float var  = rq[0] * (1.0f / 32768.0f) - mean * mean;
        float scale = gamma[c] * rsqrtf(var + 1e-5f);
        sc[c] = scale;
        sh[c] = beta[c] - mean * scale;
    }
}

// ---------------------------------------------------------------------------
// bngelu body: bf16 ydw -> BN + exact GELU -> x1 hi-only frags.
// ---------------------------------------------------------------------------
__device__ void bngelu_body(
    int bid, int tid,
    const unsigned short* __restrict__ ydwb, const float* __restrict__ sc,
    const float* __restrict__ sh, unsigned short* __restrict__ dst)
{
    int idx = bid * 256 + tid;   // 32768*16
    int r = idx >> 4, k8 = (idx & 15) * 8;
    uint4 yv = *(const uint4*)(ydwb + (size_t)r * 128 + k8);
    const unsigned* cc = (const unsigned*)&yv;
    float t[8];
    #pragma unroll
    for (int j = 0; j < 4; ++j) {
        t[2 * j]     = bfd(cc[j]);
        t[2 * j + 1] = __builtin_bit_cast(float, cc[j] & 0xFFFF0000u);
    }
    float s[8], h[8];
    *(float4*)(s)     = *(const float4*)(sc + k8);
    *(float4*)(s + 4) = *(const float4*)(sc + k8 + 4);
    *(float4*)(h)     = *(const float4*)(sh + k8);
    *(float4*)(h + 4) = *(const float4*)(sh + k8 + 4);
    #pragma unroll
    for (int i = 0; i < 8; ++i) t[i] = gelu_exact(t[i] * s[i] + h[i]);
    uint4 hi = pack8hi(t);
    int rt = r >> 4, kc = k8 >> 5, lp = (r & 15) + ((k8 & 31) >> 3) * 16;
    size_t base = ((size_t)rt * 4 + kc) * 512 + lp * 8;
    *(uint4*)(dst + base) = hi;
}

// ---------------------------------------------------------------------------
// Frag-stream MFMA GEMM body.
// ALO/WLO: whether A / W carry a lo (bf16 residual) stream.
// MODE 0: fp32 row-major + bias. MODE 3: bf16 padded [b][66][66][128].
// MODE 4: bf16 split store: tiles 0..8 -> offs (ld 144), 9..13 -> msk (ld 72).
// ---------------------------------------------------------------------------
template<int KDIM, int NT_TOT, int NT_W, int MODE, int NV, int ALO, int WLO>
__device__ void fgemm_body(
    int bx, int by, int tid,
    const unsigned short* __restrict__ AF, const unsigned short* __restrict__ WF,
    const float* __restrict__ bias, float* __restrict__ C, int ldc,
    unsigned short* __restrict__ OF, const float* __restrict__ bias2,
    float* __restrict__ C2)
{
    constexpr int KC = KDIM / 32;
    constexpr int ABLK = ALO ? 128 : 64;   // bf8 units per (rt,kc) block
    int lane = tid & 63, w = tid >> 6;
    int rt0 = bx * 8 + w * 2;      // 2 rowtiles per wave
    int t0 = by * NT_W;            // n-tile chunk base

    f32x4 acc[2][NT_W];
    #pragma unroll
    for (int rt = 0; rt < 2; ++rt)
        #pragma unroll
        for (int t = 0; t < NT_W; ++t) acc[rt][t] = (f32x4){0.f, 0.f, 0.f, 0.f};

    const bf8_t* Ab0 = (const bf8_t*)AF + (size_t)rt0 * KC * ABLK + lane;
    const bf8_t* Ab1 = Ab0 + KC * ABLK;
    const bf8_t* WHp = (const bf8_t*)WF + lane;
    const bf8_t* WLp = WHp + KC * NT_TOT * 64;

    #pragma unroll
    for (int kc = 0; kc < KC; ++kc) {
        bf8_t a0h = Ab0[kc * ABLK];
        bf8_t a1h = Ab1[kc * ABLK];
        bf8_t a0l, a1l;
        if (ALO) { a0l = Ab0[kc * ABLK + 64]; a1l = Ab1[kc * ABLK + 64]; }
        #pragma unroll
        for (int t = 0; t < NT_W; ++t) {
            int tg = t0 + t;
            if (tg < NT_TOT) {
                bf8_t wh = WHp[(kc * NT_TOT + tg) * 64];
                acc[0][t] = __builtin_amdgcn_mfma_f32_16x16x32_bf16(wh, a0h, acc[0][t], 0, 0, 0);
                acc[1][t] = __builtin_amdgcn_mfma_f32_16x16x32_bf16(wh, a1h, acc[1][t], 0, 0, 0);
                if (WLO) {
                    bf8_t wl = WLp[(kc * NT_TOT + tg) * 64];
                    acc[0][t] = __builtin_amdgcn_mfma_f32_16x16x32_bf16(wl, a0h, acc[0][t], 0, 0, 0);
                    acc[1][t] = __builtin_amdgcn_mfma_f32_16x16x32_bf16(wl, a1h, acc[1][t], 0, 0, 0);
                }
                if (ALO) {
                    acc[0][t] = __builtin_amdgcn_mfma_f32_16x16x32_bf16(wh, a0l, acc[0][t], 0, 0, 0);
                    acc[1][t] = __builtin_amdgcn_mfma_f32_16x16x32_bf16(wh, a1l, acc[1][t], 0, 0, 0);
                }
            }
        }
    }

    #pragma unroll
    for (int rt = 0; rt < 2; ++rt) {
        if (MODE == 0) {
            int m = (rt0 + rt) * 16 + (lane & 15);
            #pragma unroll
            for (int t = 0; t < NT_W; ++t) {
                int tg = t0 + t;
                int nb = tg * 16 + ((lane >> 4) << 2);
                if (tg < NT_TOT && nb + 4 <= NV) {
                    float4 bb = *(const float4*)(bias + nb);
                    f32x4 a = acc[rt][t];
                    float4 v = {a[0] + bb.x, a[1] + bb.y, a[2] + bb.z, a[3] + bb.w};
                    *(float4*)(C + (size_t)m * ldc + nb) = v;
                }
            }
        } else if (MODE == 3) {
            // bf16 store into zero-padded [b][66][66][128]
            unsigned short* Cp = (unsigned short*)C;
            int m = (rt0 + rt) * 16 + (lane & 15);
            int bb_ = m >> 12, hwm = m & 4095;
            size_t rowb = (((size_t)bb_ * 66 + (hwm >> 6) + 1) * 66 + (hwm & 63) + 1) * 128;
            #pragma unroll
            for (int t = 0; t < NT_W; ++t) {
                int tg = t0 + t;
                int nb = tg * 16 + ((lane >> 4) << 2);
                if (tg < NT_TOT) {
                    float4 bb = *(const float4*)(bias + nb);
                    f32x4 a = acc[rt][t];
                    ushort4 v;
                    v.x = bf16c(a[0] + bb.x); v.y = bf16c(a[1] + bb.y);
                    v.z = bf16c(a[2] + bb.z); v.w = bf16c(a[3] + bb.w);
                    *(ushort4*)(Cp + rowb + nb) = v;
                }
            }
        } else if (MODE == 4) {
            // bf16 split store: offs (C, ld 144) and msk (C2, ld 72)
            unsigned short* Co = (unsigned short*)C;
            unsigned short* Cm = (unsigned short*)C2;
            int m = (rt0 + rt) * 16 + (lane & 15);
            #pragma unroll
            for (int t = 0; t < NT_W; ++t) {
                int tg = t0 + t;
                if (tg < NT_TOT) {
                    int nb = tg * 16 + ((lane >> 4) << 2);
                    f32x4 a = acc[rt][t];
                    if (nb < 144) {
                        float4 bb = *(const float4*)(bias + nb);
                        ushort4 v;
                        v.x = bf16c(a[0] + bb.x); v.y = bf16c(a[1] + bb.y);
                        v.z = bf16c(a[2] + bb.z); v.w = bf16c(a[3] + bb.w);
                        *(ushort4*)(Co + (size_t)m * 144 + nb) = v;
                    } else {
                        int col = nb - 144;
                        if (col + 4 <= 72) {
                            float4 bb = *(const float4*)(bias2 + col);
                            ushort4 v;
                            v.x = bf16c(a[0] + bb.x); v.y = bf16c(a[1] + bb.y);
                            v.z = bf16c(a[2] + bb.z); v.w = bf16c(a[3] + bb.w);
                            *(ushort4*)(Cm + (size_t)m * 72 + col) = v;
                        }
                    }
                }
            }
        }
    }
}

template<int KDIM, int NT_TOT, int NT_W, int MODE, int NV, int ALO, int WLO>
__global__ __launch_bounds__(256) void k_fgemm(
    const unsigned short* __restrict__ AF, const unsigned short* __restrict__ WF,
    const float* __restrict__ bias, float* __restrict__ C, int ldc,
    unsigned short* __restrict__ OF, const float* __restrict__ bias2,
    float* __restrict__ C2)
{
    fgemm_body<KDIM, NT_TOT, NT_W, MODE, NV, ALO, WLO>(
        blockIdx.x, blockIdx.y, threadIdx.x, AF, WF, bias, C, ldc, OF, bias2, C2);
}

// K_bp: merged bngelu (2048 blocks) + proj GEMM (1024 blocks). grid 3072.
__global__ __launch_bounds__(256) void k_bp(
    const unsigned short* __restrict__ ydwb, const float* __restrict__ sc,
    const float* __restrict__ sh, unsigned short* __restrict__ x1f,
    const unsigned short* __restrict__ inpf, const unsigned short* __restrict__ wprojf,
    const float* __restrict__ bproj, unsigned short* __restrict__ xpad)
{
    int bid = blockIdx.x;
    if (bid < 2048) {
        bngelu_body(bid, threadIdx.x, ydwb, sc, sh, x1f);
    } else {
        int pbid = bid - 2048;
        fgemm_body<128, 8, 2, 3, 128, 0, 0>(pbid & 255, pbid >> 8, threadIdx.x,
            inpf, wprojf, bproj, (float*)xpad, 0, nullptr, nullptr, nullptr);
    }
}

// ---------------------------------------------------------------------------
// K6: DCNv3 core. thread = (pos, g), 16 channels. grid 1024, block 256.
// bf16 xpad gathers, bf16 offs/msk inputs, clamped addressing.
// Softmax once per (pos,g). Output packed as fc1 hi-only A-frags.
// ---------------------------------------------------------------------------
__global__ __launch_bounds__(256) void k_dcn(
    const unsigned short* __restrict__ xpad, const unsigned short* __restrict__ offs,
    const unsigned short* __restrict__ msk, unsigned short* __restrict__ dcnf)
{
    int u = blockIdx.x * 256 + threadIdx.x;  // 32768*8
    int g = u & 7;
    int pos = u >> 3;
    int b = pos >> 12, hw = pos & 4095, h = hw >> 6, w = hw & 63;

    const unsigned short* ml = msk + (size_t)pos * 72 + g * 9;
    float e[9];
    float mx = -1e30f;
    #pragma unroll
    for (int p = 0; p < 9; ++p) { e[p] = bfd((unsigned)ml[p]); mx = fmaxf(mx, e[p]); }
    float ssum = 0.f;
    #pragma unroll
    for (int p = 0; p < 9; ++p) { e[p] = __expf(e[p] - mx); ssum += e[p]; }
    float inv = 1.0f / ssum;

    const unsigned short* ob = offs + (size_t)pos * 144 + g * 18;
    const unsigned short* xb = xpad + (size_t)b * 557568 + g * 16;  // 66*66*128/b

    float acc[16];
    #pragma unroll
    for (int i = 0; i < 16; ++i) acc[i] = 0.f;

    #pragma unroll
    for (int p = 0; p < 9; ++p) {
        unsigned dpair = *(const unsigned*)(ob + p * 2);
        float dx = bfd(dpair);
        float dy = __builtin_bit_cast(float, dpair & 0xFFFF0000u);
        float px = (float)(w + (p % 3)) + dx;   // padded-grid coords
        float py = (float)(h + (p / 3)) + dy;
        float x0f = floorf(px), y0f = floorf(py);
        float wx = px - x0f, wy = py - y0f;
        int ix = (int)x0f, iy = (int)y0f;
        int ix0 = max(min(ix, 65), 0),     ix1 = max(min(ix + 1, 65), 0);
        int iy0 = max(min(iy, 65), 0),     iy1 = max(min(iy + 1, 65), 0);
        int r0 = iy0 * 66, r1 = iy1 * 66;

        float mp  = e[p] * inv;
        float w11 = wy * wx * mp;
        float w10 = wy * mp - w11;
        float w01 = wx * mp - w11;
        float w00 = mp - w01 - w10 - w11;

        const unsigned short* c00 = xb + (size_t)(r0 + ix0) * 128;
        const unsigned short* c01 = xb + (size_t)(r0 + ix1) * 128;
        const unsigned short* c10 = xb + (size_t)(r1 + ix0) * 128;
        const unsigned short* c11 = xb + (size_t)(r1 + ix1) * 128;

        uint4 a00 = *(const uint4*)(c00), b00 = *(const uint4*)(c00 + 8);
        uint4 a01 = *(const uint4*)(c01), b01 = *(const uint4*)(c01 + 8);
        uint4 a10 = *(const uint4*)(c10), b10 = *(const uint4*)(c10 + 8);
        uint4 a11 = *(const uint4*)(c11), b11 = *(const uint4*)(c11 + 8);

        ufma(acc,     a00, w00); ufma(acc + 8, b00, w00);
        ufma(acc,     a01, w01); ufma(acc + 8, b01, w01);
        ufma(acc,     a10, w10); ufma(acc + 8, b10, w10);
        ufma(acc,     a11, w11); ufma(acc + 8, b11, w11);
    }

    // pack 16 channels as two hi-only frag groups
    int rt = pos >> 4, kc = g >> 1;
    int lp0 = (pos & 15) + (g & 1) * 32;
    size_t fb = ((size_t)rt * 4 + kc) * 512 + (size_t)lp0 * 8;
    uint4 hiA = pack8hi(acc);
    uint4 hiB = pack8hi(acc + 8);
    *(uint4*)(dcnf + fb)       = hiA;
    *(uint4*)(dcnf + fb + 128) = hiB;   // lp0+16
}

// ---------------------------------------------------------------------------
// K7: fused output MLP, cooperative version. block = 512 threads (8 waves),
// 4 rowtiles. Wave w: fc1 computes (rowtile w&3, hidden-chunk w>>2) — 8 of 16
// hidden tiles — into shared hid[rt][16][264]; barrier; fc2 computes
// (rowtile w&3, out-chunk w>>2) — 4 of 8 out tiles — A-frags from LDS.
// Same numeric sequence as before; 2x waves, 4x less W re-read per wave.
// ---------------------------------------------------------------------------
__global__ __launch_bounds__(512) void k_mlp(
    const unsigned short* __restrict__ dcnf, const unsigned short* __restrict__ wf1,
    const float* __restrict__ bfc1, const unsigned short* __restrict__ wf2,
    const float* __restrict__ bfc2, float* __restrict__ out)
{
    __shared__ unsigned short hid[4][16][264];   // 33 KB
    int tid = threadIdx.x;
    int lane = tid & 63, w = tid >> 6;           // 8 waves
    int rtl = w & 3, chunk = w >> 2;             // rowtile-local, chunk 0/1
    int rt = blockIdx.x * 4 + rtl;               // rowtile 0..2047
    int m = lane & 15, hi4 = (lane >> 4) << 2;

    // ---- fc1: hidden tiles chunk*8 .. chunk*8+7 ----
    f32x4 acc[8];
    #pragma unroll
    for (int t = 0; t < 8; ++t) acc[t] = (f32x4){0.f, 0.f, 0.f, 0.f};
    const bf8_t* Ab  = (const bf8_t*)dcnf + (size_t)rt * 4 * 64 + lane;  // KC=4 hi-only
    const bf8_t* WH1 = (const bf8_t*)wf1 + lane;
    const bf8_t* WL1 = WH1 + 4 * 16 * 64;
    #pragma unroll
    for (int kc = 0; kc < 4; ++kc) {
        bf8_t ah = Ab[kc * 64];
        #pragma unroll
        for (int t = 0; t < 8; ++t) {
            int tg = chunk * 8 + t;
            bf8_t wh = WH1[(kc * 16 + tg) * 64];
            bf8_t wl = WL1[(kc * 16 + tg) * 64];
            acc[t] = __builtin_amdgcn_mfma_f32_16x16x32_bf16(wh, ah, acc[t], 0, 0, 0);
            acc[t] = __builtin_amdgcn_mfma_f32_16x16x32_bf16(wl, ah, acc[t], 0, 0, 0);
        }
    }
    // GELU + bf16 -> LDS (lane holds row m, n = tg*16+hi4..+3)
    #pragma unroll
    for (int t = 0; t < 8; ++t) {
        int nb = (chunk * 8 + t) * 16 + hi4;
        float4 bb = *(const float4*)(bfc1 + nb);
        ushort4 v;
        v.x = bf16c(gelu_exact(acc[t][0] + bb.x));
        v.y = bf16c(gelu_exact(acc[t][1] + bb.y));
        v.z = bf16c(gelu_exact(acc[t][2] + bb.z));
        v.w = bf16c(gelu_exact(acc[t][3] + bb.w));
        *(ushort4*)(&hid[rtl][m][nb]) = v;
    }

    __syncthreads();

    // ---- fc2: out tiles chunk*4 .. chunk*4+3 ----
    f32x4 acc2[4];
    #pragma unroll
    for (int t = 0; t < 4; ++t) acc2[t] = (f32x4){0.f, 0.f, 0.f, 0.f};
    const bf8_t* WH2 = (const bf8_t*)wf2 + lane;
    const bf8_t* WL2 = WH2 + 8 * 8 * 64;
    #pragma unroll
    for (int kc = 0; kc < 8; ++kc) {
        // standard A-frag from LDS: row = lane&15, k8 = kc*32 + (lane>>4)*8
        bf8_t ah = *(const bf8_t*)(&hid[rtl][m][kc * 32 + (lane >> 4) * 8]);
        #pragma unroll
        for (int t = 0; t < 4; ++t) {
            int tg = chunk * 4 + t;
            bf8_t wh = WH2[(kc * 8 + tg) * 64];
            bf8_t wl = WL2[(kc * 8 + tg) * 64];
            acc2[t] = __builtin_amdgcn_mfma_f32_16x16x32_bf16(ah, wh, acc2[t], 0, 0, 0);
            acc2[t] = __builtin_amdgcn_mfma_f32_16x16x32_bf16(ah, wl, acc2[t], 0, 0, 0);
        }
    }
    // NCHW transposed fp32 store: lane holds m4 = rt*16+hi4(+j), n = tg*16+m
    int m4 = rt * 16 + hi4;
    int b = m4 >> 12, hw = m4 & 4095;
    #pragma unroll
    for (int t = 0; t < 4; ++t) {
        int n = (chunk * 4 + t) * 16 + m;
        float bb = bfc2[n];
        f32x4 a = acc2[t];
        float4 v = {a[0] + bb, a[1] + bb, a[2] + bb, a[3] + bb};
        *(float4*)(out + (((size_t)(b * 128 + n)) << 12) + hw) = v;
    }
}

// ---------------------------------------------------------------------------
extern "C" void kernel_launch(void* const* d_in, const int* in_sizes, int n_in,
                              void* d_out, int out_size, void* d_ws, size_t ws_size,
                              hipStream_t stream)
{
    const float* inp   = (const float*)d_in[0];
    const float* wproj = (const float*)d_in[1];
    const float* bproj = (const float*)d_in[2];
    const float* dww   = (const float*)d_in[3];
    const float* dwb   = (const float*)d_in[4];
    const float* gamma = (const float*)d_in[5];
    const float* beta  = (const float*)d_in[6];
    const float* woff  = (const float*)d_in[7];
    const float* boff  = (const float*)d_in[8];
    const float* wmask = (const float*)d_in[9];
    const float* bmask = (const float*)d_in[10];
    const float* wfc1  = (const float*)d_in[11];
    const float* bfc1  = (const float*)d_in[12];
    const float* wfc2  = (const float*)d_in[13];
    const float* bfc2  = (const float*)d_in[14];
    float* out = (float*)d_out;
    float* ws  = (float*)d_ws;

    // Region P: xpad (bf16) + offs (bf16)
    unsigned short* xpad = (unsigned short*)ws;              // 4,460,544 ush [proj..dcn]
    unsigned short* offs = (unsigned short*)(ws + 2230272);  // 4,718,592 ush [offmask..dcn]
    // Region A at ws+9179136: inpf [pd..bp-proj], dcnf [dcn..mlp]
    unsigned short* inpf  = (unsigned short*)(ws + 9179136);   // 4,194,304 ush hi-only
    unsigned short* dcnf  = (unsigned short*)(ws + 9179136);   // 4,194,304 ush hi-only
    unsigned short* x1f   = (unsigned short*)(ws + 13373440);  // 4,194,304 ush hi-only [bp..offmask]
    unsigned short* ydwb  = (unsigned short*)(ws + 15470592);  // 4,194,304 ush bf16 [pd..bp]
    // Rest
    unsigned short* msk = (unsigned short*)(ws + 17567744);  // 2,359,296 ush
    float* psum = ws + 19927040;                         // 65,536 f
    float* psq  = ws + 19992576;                         // 65,536 f
    float* scs  = ws + 20058112;                         // 128 f
    float* shs  = ws + 20058240;                         // 128 f
    unsigned short* wfr = (unsigned short*)(ws + 20058368);  // 176,128 ush

    unsigned short* wproj_f = wfr;            // hi-only, 16384
    unsigned short* womb_f  = wfr + 16384;    // hi-only combined, 28672
    unsigned short* wfc1_f  = wfr + 45056;    // hi/lo, 65536
    unsigned short* wfc2_f  = wfr + 110592;   // hi/lo, 65536

    k_pd<<<2744, 256, 0, stream>>>(inp, inpf, xpad, wproj, woff, wmask, wfc1, wfc2,
                                   wfr, dww, dwb, ydwb, psum, psq);
    k_bnstats<<<128, 256, 0, stream>>>(psum, psq, gamma, beta, scs, shs);
    k_bp<<<3072, 256, 0, stream>>>(ydwb, scs, shs, x1f, inpf, wproj_f, bproj, xpad);
    k_fgemm<128, 14, 4, 4, 224, 0, 0><<<dim3(256, 4), 256, 0, stream>>>(x1f, womb_f, boff, (float*)offs, 144, nullptr, bmask, (float*)msk);
    k_dcn<<<1024, 256, 0, stream>>>(xpad, offs, msk, dcnf);
    k_mlp<<<512, 512, 0, stream>>>(dcnf, wfc1_f, bfc1, wfc2_f, bfc2, out);
}

// Round 13
// 96.590 us; speedup vs baseline: 1.1831x; 1.0900x over previous
//
#include <hip/hip_runtime.h>
#include <math.h>

#define NPOS  32768      // B*H*W
#define CDIM  128
#define HS    64
#define WSZ   64

typedef __bf16 bf8_t  __attribute__((ext_vector_type(8)));
typedef float  f32x4  __attribute__((ext_vector_type(4)));

__device__ __forceinline__ float gelu_exact(float x) {
    return 0.5f * x * (1.0f + erff(x * 0.70710678118654752f));
}

__device__ __forceinline__ unsigned short bf16c(float v) {
    return __builtin_bit_cast(unsigned short, (__bf16)v);
}

__device__ __forceinline__ uint4 pack8hi(const float* v) {
    unsigned hh[8];
    #pragma unroll
    for (int i = 0; i < 8; ++i) hh[i] = (unsigned)bf16c(v[i]);
    return make_uint4(hh[0] | (hh[1] << 16), hh[2] | (hh[3] << 16),
                      hh[4] | (hh[5] << 16), hh[6] | (hh[7] << 16));
}

__device__ __forceinline__ float bfd(unsigned u) {        // low 16 bits as bf16
    return __builtin_bit_cast(float, u << 16);
}

// unpack uint4 (8 bf16) and fma into acc[8] with weight
__device__ __forceinline__ void ufma(float* acc, uint4 c, float wgt) {
    const unsigned* cc = (const unsigned*)&c;
    #pragma unroll
    for (int j = 0; j < 4; ++j) {
        acc[2 * j]     += __builtin_bit_cast(float, cc[j] << 16) * wgt;
        acc[2 * j + 1] += __builtin_bit_cast(float, cc[j] & 0xFFFF0000u) * wgt;
    }
}

// ---------------------------------------------------------------------------
// A-frag layouts (K=KC*32):
//  hi/lo buffers: block(rt,kc) = 1024 ush (hi 512 | lo 512)
//  hi-only buffers: block(rt,kc) = 512 ush
//  elem: lane*8 + i, lane = (row%16) + ((k%32)/8)*16, i = k%8
// ---------------------------------------------------------------------------

// ---------------------------------------------------------------------------
// prep body: blocks [0,2048) aprep: inp -> hi-only frags
//            [2048,2178) border: zero 1-px ring of bf16 xpad
//            [2178,2232) wprep: weights -> frag bf16
// ---------------------------------------------------------------------------
__device__ void prep_body(
    int bid, int tid,
    const float* __restrict__ inp, unsigned short* __restrict__ inpf,
    unsigned short* __restrict__ xpad,
    const float* __restrict__ w0, const float* __restrict__ w1,
    const float* __restrict__ w2, const float* __restrict__ w3,
    const float* __restrict__ w4, unsigned short* __restrict__ wb)
{
    if (bid < 2048) {
        int idx = bid * 256 + tid;                  // 32768*16
        int r = idx >> 4, k8 = (idx & 15) * 8;
        float t[8];
        *(float4*)(t)     = *(const float4*)(inp + (size_t)r * 128 + k8);
        *(float4*)(t + 4) = *(const float4*)(inp + (size_t)r * 128 + k8 + 4);
        uint4 hi = pack8hi(t);
        int rt = r >> 4, kc = k8 >> 5, lp = (r & 15) + ((k8 & 31) >> 3) * 16;
        size_t base = ((size_t)rt * 4 + kc) * 512 + lp * 8;
        *(uint4*)(inpf + base) = hi;
    } else if (bid < 2178) {
        int idx = (bid - 2048) * 256 + tid;         // 2080 cells * 16
        if (idx < 33280) {
            int c8 = (idx & 15) * 8;
            int cell = idx >> 4;
            int b = cell / 260, r = cell % 260;
            int h, w;
            if (r < 66)       { h = 0;  w = r; }
            else if (r < 132) { h = 65; w = r - 66; }
            else { int rr = r - 132; h = 1 + (rr >> 1); w = (rr & 1) * 65; }
            size_t o = (((size_t)b * 66 + h) * 66 + w) * 128 + c8;
            *(uint4*)(xpad + o) = make_uint4(0u, 0u, 0u, 0u);
        }
    } else {
        int sub = (bid - 2178) * 4 + (tid >> 6);    // 0..215
        int lane = tid & 63;
        int NT, K, local; unsigned short* out; bool hl; bool comb = false;
        const float* W = nullptr; int N = 0;
        if (sub < 32)       { NT = 8;  K = 128; out = wb;          local = sub;       hl = false; W = w0; N = 128; }
        else if (sub < 88)  { NT = 14; K = 128; out = wb + 16384;  local = sub - 32;  hl = false; comb = true; }
        else if (sub < 152) { NT = 16; K = 128; out = wb + 45056;  local = sub - 88;  hl = true;  W = w3; N = 256; }
        else                { NT = 8;  K = 256; out = wb + 110592; local = sub - 152; hl = true;  W = w4; N = 128; }
        int KC = K / 32;
        int unit = KC * NT * 512;
        int kc = local / NT, t = local % NT;
        int nt = t * 16 + (lane & 15);
        const float* Wp = W; int n = nt, Nv = N;
        if (comb) {
            if (t < 9) { Wp = w1; n = nt;       Nv = 144; }
            else       { Wp = w2; n = nt - 144; Nv = 72;  }
        }
        int kb = kc * 32 + (lane >> 4) * 8;
        size_t base = ((size_t)local * 64 + lane) * 8;
        #pragma unroll
        for (int i = 0; i < 8; ++i) {
            float v = (n < Nv) ? Wp[(size_t)n * K + kb + i] : 0.f;
            __bf16 h = (__bf16)v;
            out[base + i] = __builtin_bit_cast(unsigned short, h);
            if (hl) {
                __bf16 l = (__bf16)(v - (float)h);
                out[unit + base + i] = __builtin_bit_cast(unsigned short, l);
            }
        }
    }
}

// ---------------------------------------------------------------------------
// dwconv body: depthwise 3x3 (NHWC) -> bf16 ydw + partial BN sums (fp32)
// ---------------------------------------------------------------------------
__device__ void dwconv_body(
    int blk, int tid,
    const float* __restrict__ inp, const float* __restrict__ dww,
    const float* __restrict__ dwb, unsigned short* __restrict__ ydwb,
    float* __restrict__ psum, float* __restrict__ psq)
{
    int b = blk >> 6, h = blk & 63;
    int c4 = (tid & 31) * 4;
    int wg = tid >> 5;               // 0..7

    float wreg[4][9];
    #pragma unroll
    for (int cc = 0; cc < 4; ++cc)
        #pragma unroll
        for (int p = 0; p < 9; ++p)
            wreg[cc][p] = dww[(c4 + cc) * 9 + p];
    float bia[4];
    #pragma unroll
    for (int cc = 0; cc < 4; ++cc) bia[cc] = dwb[c4 + cc];

    float s4[4] = {0,0,0,0}, q4[4] = {0,0,0,0};
    const float* ibase = inp + (size_t)(b << 12) * CDIM;

    for (int i = 0; i < 8; ++i) {
        int w = wg + i * 8;
        float acc[4] = {bia[0], bia[1], bia[2], bia[3]};
        #pragma unroll
        for (int ky = 0; ky < 3; ++ky) {
            int yy = h + ky - 1;
            if (yy < 0 || yy >= HS) continue;
            #pragma unroll
            for (int kx = 0; kx < 3; ++kx) {
                int xx = w + kx - 1;
                if (xx < 0 || xx >= WSZ) continue;
                float4 v = *(const float4*)(ibase + (size_t)(yy * 64 + xx) * CDIM + c4);
                int p = ky * 3 + kx;
                acc[0] += v.x * wreg[0][p];
                acc[1] += v.y * wreg[1][p];
                acc[2] += v.z * wreg[2][p];
                acc[3] += v.w * wreg[3][p];
            }
        }
        ushort4 o;
        o.x = bf16c(acc[0]); o.y = bf16c(acc[1]);
        o.z = bf16c(acc[2]); o.w = bf16c(acc[3]);
        *(ushort4*)(ydwb + ((size_t)(b << 12) + h * 64 + w) * CDIM + c4) = o;
        #pragma unroll
        for (int cc = 0; cc < 4; ++cc) { s4[cc] += acc[cc]; q4[cc] += acc[cc] * acc[cc]; }
    }

    __shared__ float ls[8][128], lq[8][128];
    #pragma unroll
    for (int cc = 0; cc < 4; ++cc) { ls[wg][c4 + cc] = s4[cc]; lq[wg][c4 + cc] = q4[cc]; }
    __syncthreads();
    if (tid < 128) {
        float s = 0.f, q = 0.f;
        #pragma unroll
        for (int r = 0; r < 8; ++r) { s += ls[r][tid]; q += lq[r][tid]; }
        psum[blk * 128 + tid] = s;
        psq [blk * 128 + tid] = q;
    }
}

// K_pd: merged prep (2232 blocks) + dwconv (512 blocks). grid 2744.
__global__ __launch_bounds__(256) void k_pd(
    const float* __restrict__ inp, unsigned short* __restrict__ inpf,
    unsigned short* __restrict__ xpad,
    const float* __restrict__ w0, const float* __restrict__ w1,
    const float* __restrict__ w2, const float* __restrict__ w3,
    const float* __restrict__ w4, unsigned short* __restrict__ wb,
    const float* __restrict__ dww, const float* __restrict__ dwb,
    unsigned short* __restrict__ ydwb, float* __restrict__ psum,
    float* __restrict__ psq)
{
    int bid = blockIdx.x;
    if (bid < 2232) prep_body(bid, threadIdx.x, inp, inpf, xpad, w0, w1, w2, w3, w4, wb);
    else            dwconv_body(bid - 2232, threadIdx.x, inp, dww, dwb, ydwb, psum, psq);
}

// ---------------------------------------------------------------------------
// K2: finalize BN stats -> scale/shift per channel.
// ---------------------------------------------------------------------------
__global__ __launch_bounds__(256) void k_bnstats(
    const float* __restrict__ psum, const float* __restrict__ psq,
    const float* __restrict__ gamma, const float* __restrict__ beta,
    float* __restrict__ sc, float* __restrict__ sh)
{
    int c = blockIdx.x;
    int t = threadIdx.x;
    float s = psum[t * 128 + c] + psum[(t + 256) * 128 + c];
    float q = psq [t * 128 + c] + psq [(t + 256) * 128 + c];
    __shared__ float rs[256], rq[256];
    rs[t] = s; rq[t] = q; __syncthreads();
    for (int off = 128; off > 0; off >>= 1) {
        if (t < off) { rs[t] += rs[t + off]; rq[t] += rq[t + off]; }
        __syncthreads();
    }
    if (t == 0) {
        float mean = rs[0] * (1.0f / 32768.0f);
        float var  = rq[0] * (1.0f / 32768.0f) - mean * mean;
        float scale = gamma[c] * rsqrtf(var + 1e-5f);
        sc[c] = scale;
        sh[c] = beta[c] - mean * scale;
    }
}

// ---------------------------------------------------------------------------
// bngelu body: bf16 ydw -> BN + exact GELU -> x1 hi-only frags.
// ---------------------------------------------------------------------------
__device__ void bngelu_body(
    int bid, int tid,
    const unsigned short* __restrict__ ydwb, const float* __restrict__ sc,
    const float* __restrict__ sh, unsigned short* __restrict__ dst)
{
    int idx = bid * 256 + tid;   // 32768*16
    int r = idx >> 4, k8 = (idx & 15) * 8;
    uint4 yv = *(const uint4*)(ydwb + (size_t)r * 128 + k8);
    const unsigned* cc = (const unsigned*)&yv;
    float t[8];
    #pragma unroll
    for (int j = 0; j < 4; ++j) {
        t[2 * j]     = bfd(cc[j]);
        t[2 * j + 1] = __builtin_bit_cast(float, cc[j] & 0xFFFF0000u);
    }
    float s[8], h[8];
    *(float4*)(s)     = *(const float4*)(sc + k8);
    *(float4*)(s + 4) = *(const float4*)(sc + k8 + 4);
    *(float4*)(h)     = *(const float4*)(sh + k8);
    *(float4*)(h + 4) = *(const float4*)(sh + k8 + 4);
    #pragma unroll
    for (int i = 0; i < 8; ++i) t[i] = gelu_exact(t[i] * s[i] + h[i]);
    uint4 hi = pack8hi(t);
    int rt = r >> 4, kc = k8 >> 5, lp = (r & 15) + ((k8 & 31) >> 3) * 16;
    size_t base = ((size_t)rt * 4 + kc) * 512 + lp * 8;
    *(uint4*)(dst + base) = hi;
}

// ---------------------------------------------------------------------------
// Frag-stream MFMA GEMM body.
// ALO/WLO: whether A / W carry a lo (bf16 residual) stream.
// MODE 0: fp32 row-major + bias. MODE 3: bf16 padded [b][66][66][128].
// MODE 4: bf16 split store: tiles 0..8 -> offs (ld 144), 9..13 -> msk (ld 72).
// ---------------------------------------------------------------------------
template<int KDIM, int NT_TOT, int NT_W, int MODE, int NV, int ALO, int WLO>
__device__ void fgemm_body(
    int bx, int by, int tid,
    const unsigned short* __restrict__ AF, const unsigned short* __restrict__ WF,
    const float* __restrict__ bias, float* __restrict__ C, int ldc,
    unsigned short* __restrict__ OF, const float* __restrict__ bias2,
    float* __restrict__ C2)
{
    constexpr int KC = KDIM / 32;
    constexpr int ABLK = ALO ? 128 : 64;   // bf8 units per (rt,kc) block
    int lane = tid & 63, w = tid >> 6;
    int rt0 = bx * 8 + w * 2;      // 2 rowtiles per wave
    int t0 = by * NT_W;            // n-tile chunk base

    f32x4 acc[2][NT_W];
    #pragma unroll
    for (int rt = 0; rt < 2; ++rt)
        #pragma unroll
        for (int t = 0; t < NT_W; ++t) acc[rt][t] = (f32x4){0.f, 0.f, 0.f, 0.f};

    const bf8_t* Ab0 = (const bf8_t*)AF + (size_t)rt0 * KC * ABLK + lane;
    const bf8_t* Ab1 = Ab0 + KC * ABLK;
    const bf8_t* WHp = (const bf8_t*)WF + lane;
    const bf8_t* WLp = WHp + KC * NT_TOT * 64;

    #pragma unroll
    for (int kc = 0; kc < KC; ++kc) {
        bf8_t a0h = Ab0[kc * ABLK];
        bf8_t a1h = Ab1[kc * ABLK];
        bf8_t a0l, a1l;
        if (ALO) { a0l = Ab0[kc * ABLK + 64]; a1l = Ab1[kc * ABLK + 64]; }
        #pragma unroll
        for (int t = 0; t < NT_W; ++t) {
            int tg = t0 + t;
            if (tg < NT_TOT) {
                bf8_t wh = WHp[(kc * NT_TOT + tg) * 64];
                acc[0][t] = __builtin_amdgcn_mfma_f32_16x16x32_bf16(wh, a0h, acc[0][t], 0, 0, 0);
                acc[1][t] = __builtin_amdgcn_mfma_f32_16x16x32_bf16(wh, a1h, acc[1][t], 0, 0, 0);
                if (WLO) {
                    bf8_t wl = WLp[(kc * NT_TOT + tg) * 64];
                    acc[0][t] = __builtin_amdgcn_mfma_f32_16x16x32_bf16(wl, a0h, acc[0][t], 0, 0, 0);
                    acc[1][t] = __builtin_amdgcn_mfma_f32_16x16x32_bf16(wl, a1h, acc[1][t], 0, 0, 0);
                }
                if (ALO) {
                    acc[0][t] = __builtin_amdgcn_mfma_f32_16x16x32_bf16(wh, a0l, acc[0][t], 0, 0, 0);
                    acc[1][t] = __builtin_amdgcn_mfma_f32_16x16x32_bf16(wh, a1l, acc[1][t], 0, 0, 0);
                }
            }
        }
    }

    #pragma unroll
    for (int rt = 0; rt < 2; ++rt) {
        if (MODE == 0) {
            int m = (rt0 + rt) * 16 + (lane & 15);
            #pragma unroll
            for (int t = 0; t < NT_W; ++t) {
                int tg = t0 + t;
                int nb = tg * 16 + ((lane >> 4) << 2);
                if (tg < NT_TOT && nb + 4 <= NV) {
                    float4 bb = *(const float4*)(bias + nb);
                    f32x4 a = acc[rt][t];
                    float4 v = {a[0] + bb.x, a[1] + bb.y, a[2] + bb.z, a[3] + bb.w};
                    *(float4*)(C + (size_t)m * ldc + nb) = v;
                }
            }
        } else if (MODE == 3) {
            // bf16 store into zero-padded [b][66][66][128]
            unsigned short* Cp = (unsigned short*)C;
            int m = (rt0 + rt) * 16 + (lane & 15);
            int bb_ = m >> 12, hwm = m & 4095;
            size_t rowb = (((size_t)bb_ * 66 + (hwm >> 6) + 1) * 66 + (hwm & 63) + 1) * 128;
            #pragma unroll
            for (int t = 0; t < NT_W; ++t) {
                int tg = t0 + t;
                int nb = tg * 16 + ((lane >> 4) << 2);
                if (tg < NT_TOT) {
                    float4 bb = *(const float4*)(bias + nb);
                    f32x4 a = acc[rt][t];
                    ushort4 v;
                    v.x = bf16c(a[0] + bb.x); v.y = bf16c(a[1] + bb.y);
                    v.z = bf16c(a[2] + bb.z); v.w = bf16c(a[3] + bb.w);
                    *(ushort4*)(Cp + rowb + nb) = v;
                }
            }
        } else if (MODE == 4) {
            // bf16 split store: offs (C, ld 144) and msk (C2, ld 72)
            unsigned short* Co = (unsigned short*)C;
            unsigned short* Cm = (unsigned short*)C2;
            int m = (rt0 + rt) * 16 + (lane & 15);
            #pragma unroll
            for (int t = 0; t < NT_W; ++t) {
                int tg = t0 + t;
                if (tg < NT_TOT) {
                    int nb = tg * 16 + ((lane >> 4) << 2);
                    f32x4 a = acc[rt][t];
                    if (nb < 144) {
                        float4 bb = *(const float4*)(bias + nb);
                        ushort4 v;
                        v.x = bf16c(a[0] + bb.x); v.y = bf16c(a[1] + bb.y);
                        v.z = bf16c(a[2] + bb.z); v.w = bf16c(a[3] + bb.w);
                        *(ushort4*)(Co + (size_t)m * 144 + nb) = v;
                    } else {
                        int col = nb - 144;
                        if (col + 4 <= 72) {
                            float4 bb = *(const float4*)(bias2 + col);
                            ushort4 v;
                            v.x = bf16c(a[0] + bb.x); v.y = bf16c(a[1] + bb.y);
                            v.z = bf16c(a[2] + bb.z); v.w = bf16c(a[3] + bb.w);
                            *(ushort4*)(Cm + (size_t)m * 72 + col) = v;
                        }
                    }
                }
            }
        }
    }
}

template<int KDIM, int NT_TOT, int NT_W, int MODE, int NV, int ALO, int WLO>
__global__ __launch_bounds__(256) void k_fgemm(
    const unsigned short* __restrict__ AF, const unsigned short* __restrict__ WF,
    const float* __restrict__ bias, float* __restrict__ C, int ldc,
    unsigned short* __restrict__ OF, const float* __restrict__ bias2,
    float* __restrict__ C2)
{
    fgemm_body<KDIM, NT_TOT, NT_W, MODE, NV, ALO, WLO>(
        blockIdx.x, blockIdx.y, threadIdx.x, AF, WF, bias, C, ldc, OF, bias2, C2);
}

// K_bp: merged bngelu (2048 blocks) + proj GEMM (1024 blocks). grid 3072.
__global__ __launch_bounds__(256) void k_bp(
    const unsigned short* __restrict__ ydwb, const float* __restrict__ sc,
    const float* __restrict__ sh, unsigned short* __restrict__ x1f,
    const unsigned short* __restrict__ inpf, const unsigned short* __restrict__ wprojf,
    const float* __restrict__ bproj, unsigned short* __restrict__ xpad)
{
    int bid = blockIdx.x;
    if (bid < 2048) {
        bngelu_body(bid, threadIdx.x, ydwb, sc, sh, x1f);
    } else {
        int pbid = bid - 2048;
        fgemm_body<128, 8, 2, 3, 128, 0, 0>(pbid & 255, pbid >> 8, threadIdx.x,
            inpf, wprojf, bproj, (float*)xpad, 0, nullptr, nullptr, nullptr);
    }
}

// ---------------------------------------------------------------------------
// K6: DCNv3 core. thread = (pos, g), 16 channels. grid 1024, block 256.
// bf16 xpad gathers, bf16 offs/msk inputs, clamped addressing.
// Softmax once per (pos,g). Output packed as fc1 hi-only A-frags.
// ---------------------------------------------------------------------------
__global__ __launch_bounds__(256) void k_dcn(
    const unsigned short* __restrict__ xpad, const unsigned short* __restrict__ offs,
    const unsigned short* __restrict__ msk, unsigned short* __restrict__ dcnf)
{
    int u = blockIdx.x * 256 + threadIdx.x;  // 32768*8
    int g = u & 7;
    int pos = u >> 3;
    int b = pos >> 12, hw = pos & 4095, h = hw >> 6, w = hw & 63;

    const unsigned short* ml = msk + (size_t)pos * 72 + g * 9;
    float e[9];
    float mx = -1e30f;
    #pragma unroll
    for (int p = 0; p < 9; ++p) { e[p] = bfd((unsigned)ml[p]); mx = fmaxf(mx, e[p]); }
    float ssum = 0.f;
    #pragma unroll
    for (int p = 0; p < 9; ++p) { e[p] = __expf(e[p] - mx); ssum += e[p]; }
    float inv = 1.0f / ssum;

    const unsigned short* ob = offs + (size_t)pos * 144 + g * 18;
    const unsigned short* xb = xpad + (size_t)b * 557568 + g * 16;  // 66*66*128/b

    float acc[16];
    #pragma unroll
    for (int i = 0; i < 16; ++i) acc[i] = 0.f;

    #pragma unroll
    for (int p = 0; p < 9; ++p) {
        unsigned dpair = *(const unsigned*)(ob + p * 2);
        float dx = bfd(dpair);
        float dy = __builtin_bit_cast(float, dpair & 0xFFFF0000u);
        float px = (float)(w + (p % 3)) + dx;   // padded-grid coords
        float py = (float)(h + (p / 3)) + dy;
        float x0f = floorf(px), y0f = floorf(py);
        float wx = px - x0f, wy = py - y0f;
        int ix = (int)x0f, iy = (int)y0f;
        int ix0 = max(min(ix, 65), 0),     ix1 = max(min(ix + 1, 65), 0);
        int iy0 = max(min(iy, 65), 0),     iy1 = max(min(iy + 1, 65), 0);
        int r0 = iy0 * 66, r1 = iy1 * 66;

        float mp  = e[p] * inv;
        float w11 = wy * wx * mp;
        float w10 = wy * mp - w11;
        float w01 = wx * mp - w11;
        float w00 = mp - w01 - w10 - w11;

        const unsigned short* c00 = xb + (size_t)(r0 + ix0) * 128;
        const unsigned short* c01 = xb + (size_t)(r0 + ix1) * 128;
        const unsigned short* c10 = xb + (size_t)(r1 + ix0) * 128;
        const unsigned short* c11 = xb + (size_t)(r1 + ix1) * 128;

        uint4 a00 = *(const uint4*)(c00), b00 = *(const uint4*)(c00 + 8);
        uint4 a01 = *(const uint4*)(c01), b01 = *(const uint4*)(c01 + 8);
        uint4 a10 = *(const uint4*)(c10), b10 = *(const uint4*)(c10 + 8);
        uint4 a11 = *(const uint4*)(c11), b11 = *(const uint4*)(c11 + 8);

        ufma(acc,     a00, w00); ufma(acc + 8, b00, w00);
        ufma(acc,     a01, w01); ufma(acc + 8, b01, w01);
        ufma(acc,     a10, w10); ufma(acc + 8, b10, w10);
        ufma(acc,     a11, w11); ufma(acc + 8, b11, w11);
    }

    // pack 16 channels as two hi-only frag groups
    int rt = pos >> 4, kc = g >> 1;
    int lp0 = (pos & 15) + (g & 1) * 32;
    size_t fb = ((size_t)rt * 4 + kc) * 512 + (size_t)lp0 * 8;
    uint4 hiA = pack8hi(acc);
    uint4 hiB = pack8hi(acc + 8);
    *(uint4*)(dcnf + fb)       = hiA;
    *(uint4*)(dcnf + fb + 128) = hiB;   // lp0+16
}

// ---------------------------------------------------------------------------
// K7: fused output MLP v3. block = 512 threads (8 waves) = 2 rowtile-PAIRS.
// wave w: pr = w&1 (pair), chunk = w>>1 (0..3).
// fc1: 4 hidden tiles (chunk*4..+3) x 2 rowtiles, hi-only W -> GELU -> LDS.
// barrier. fc2: 2 out tiles (chunk*2..+1) x 2 rowtiles, hi-only W, A from LDS.
// Per-wave W: 32 KB for 2 rowtiles (was 128 KB for 1) -> 4x less W traffic,
// halved MFMAs; 4096 waves keep 4/SIMD occupancy.
// ---------------------------------------------------------------------------
__global__ __launch_bounds__(512) void k_mlp(
    const unsigned short* __restrict__ dcnf, const unsigned short* __restrict__ wf1,
    const float* __restrict__ bfc1, const unsigned short* __restrict__ wf2,
    const float* __restrict__ bfc2, float* __restrict__ out)
{
    __shared__ unsigned short hid[4][16][264];   // 4 rowtiles, 33.8 KB
    int tid = threadIdx.x;
    int lane = tid & 63, w = tid >> 6;           // 8 waves
    int pr = w & 1, chunk = w >> 1;              // pair-local, chunk 0..3
    int bp = blockIdx.x * 2 + pr;                // pair id 0..1023
    int rt0 = bp * 2;                            // rowtiles rt0, rt0+1
    int m = lane & 15, hi4 = (lane >> 4) << 2;

    // ---- fc1: hidden tiles chunk*4 .. +3, rowtiles rt0, rt0+1 ----
    f32x4 acc[2][4];
    #pragma unroll
    for (int r = 0; r < 2; ++r)
        #pragma unroll
        for (int t = 0; t < 4; ++t) acc[r][t] = (f32x4){0.f, 0.f, 0.f, 0.f};
    const bf8_t* Ab0 = (const bf8_t*)dcnf + (size_t)rt0 * 4 * 64 + lane;  // KC=4 hi-only
    const bf8_t* Ab1 = Ab0 + 4 * 64;
    const bf8_t* WH1 = (const bf8_t*)wf1 + lane;
    #pragma unroll
    for (int kc = 0; kc < 4; ++kc) {
        bf8_t a0 = Ab0[kc * 64];
        bf8_t a1 = Ab1[kc * 64];
        #pragma unroll
        for (int t = 0; t < 4; ++t) {
            int tg = chunk * 4 + t;
            bf8_t wh = WH1[(kc * 16 + tg) * 64];
            acc[0][t] = __builtin_amdgcn_mfma_f32_16x16x32_bf16(wh, a0, acc[0][t], 0, 0, 0);
            acc[1][t] = __builtin_amdgcn_mfma_f32_16x16x32_bf16(wh, a1, acc[1][t], 0, 0, 0);
        }
    }
    // GELU + bf16 -> LDS (lane holds row m, n = tg*16+hi4..+3)
    #pragma unroll
    for (int r = 0; r < 2; ++r) {
        #pragma unroll
        for (int t = 0; t < 4; ++t) {
            int nb = (chunk * 4 + t) * 16 + hi4;
            float4 bb = *(const float4*)(bfc1 + nb);
            ushort4 v;
            v.x = bf16c(gelu_exact(acc[r][t][0] + bb.x));
            v.y = bf16c(gelu_exact(acc[r][t][1] + bb.y));
            v.z = bf16c(gelu_exact(acc[r][t][2] + bb.z));
            v.w = bf16c(gelu_exact(acc[r][t][3] + bb.w));
            *(ushort4*)(&hid[pr * 2 + r][m][nb]) = v;
        }
    }

    __syncthreads();

    // ---- fc2: out tiles chunk*2 .. +1, rowtiles rt0, rt0+1 ----
    f32x4 acc2[2][2];
    #pragma unroll
    for (int r = 0; r < 2; ++r)
        #pragma unroll
        for (int t = 0; t < 2; ++t) acc2[r][t] = (f32x4){0.f, 0.f, 0.f, 0.f};
    const bf8_t* WH2 = (const bf8_t*)wf2 + lane;
    #pragma unroll
    for (int kc = 0; kc < 8; ++kc) {
        // standard A-frag from LDS: row = lane&15, k8 = kc*32 + (lane>>4)*8
        bf8_t ah0 = *(const bf8_t*)(&hid[pr * 2 + 0][m][kc * 32 + (lane >> 4) * 8]);
        bf8_t ah1 = *(const bf8_t*)(&hid[pr * 2 + 1][m][kc * 32 + (lane >> 4) * 8]);
        #pragma unroll
        for (int t = 0; t < 2; ++t) {
            int tg = chunk * 2 + t;
            bf8_t wh = WH2[(kc * 8 + tg) * 64];
            acc2[0][t] = __builtin_amdgcn_mfma_f32_16x16x32_bf16(ah0, wh, acc2[0][t], 0, 0, 0);
            acc2[1][t] = __builtin_amdgcn_mfma_f32_16x16x32_bf16(ah1, wh, acc2[1][t], 0, 0, 0);
        }
    }
    // NCHW transposed fp32 store: lane holds m4 = rt*16+hi4(+j), n = tg*16+m
    #pragma unroll
    for (int r = 0; r < 2; ++r) {
        int m4 = (rt0 + r) * 16 + hi4;
        int b = m4 >> 12, hw = m4 & 4095;
        #pragma unroll
        for (int t = 0; t < 2; ++t) {
            int n = (chunk * 2 + t) * 16 + m;
            float bb = bfc2[n];
            f32x4 a = acc2[r][t];
            float4 v = {a[0] + bb, a[1] + bb, a[2] + bb, a[3] + bb};
            *(float4*)(out + (((size_t)(b * 128 + n)) << 12) + hw) = v;
        }
    }
}

// ---------------------------------------------------------------------------
extern "C" void kernel_launch(void* const* d_in, const int* in_sizes, int n_in,
                              void* d_out, int out_size, void* d_ws, size_t ws_size,
                              hipStream_t stream)
{
    const float* inp   = (const float*)d_in[0];
    const float* wproj = (const float*)d_in[1];
    const float* bproj = (const float*)d_in[2];
    const float* dww   = (const float*)d_in[3];
    const float* dwb   = (const float*)d_in[4];
    const float* gamma = (const float*)d_in[5];
    const float* beta  = (const float*)d_in[6];
    const float* woff  = (const float*)d_in[7];
    const float* boff  = (const float*)d_in[8];
    const float* wmask = (const float*)d_in[9];
    const float* bmask = (const float*)d_in[10];
    const float* wfc1  = (const float*)d_in[11];
    const float* bfc1  = (const float*)d_in[12];
    const float* wfc2  = (const float*)d_in[13];
    const float* bfc2  = (const float*)d_in[14];
    float* out = (float*)d_out;
    float* ws  = (float*)d_ws;

    // Region P: xpad (bf16) + offs (bf16)
    unsigned short* xpad = (unsigned short*)ws;              // 4,460,544 ush [proj..dcn]
    unsigned short* offs = (unsigned short*)(ws + 2230272);  // 4,718,592 ush [offmask..dcn]
    // Region A at ws+9179136: inpf [pd..bp-proj], dcnf [dcn..mlp]
    unsigned short* inpf  = (unsigned short*)(ws + 9179136);   // 4,194,304 ush hi-only
    unsigned short* dcnf  = (unsigned short*)(ws + 9179136);   // 4,194,304 ush hi-only
    unsigned short* x1f   = (unsigned short*)(ws + 13373440);  // 4,194,304 ush hi-only [bp..offmask]
    unsigned short* ydwb  = (unsigned short*)(ws + 15470592);  // 4,194,304 ush bf16 [pd..bp]
    // Rest
    unsigned short* msk = (unsigned short*)(ws + 17567744);  // 2,359,296 ush
    float* psum = ws + 19927040;                         // 65,536 f
    float* psq  = ws + 19992576;                         // 65,536 f
    float* scs  = ws + 20058112;                         // 128 f
    float* shs  = ws + 20058240;                         // 128 f
    unsigned short* wfr = (unsigned short*)(ws + 20058368);  // 176,128 ush

    unsigned short* wproj_f = wfr;            // hi-only, 16384
    unsigned short* womb_f  = wfr + 16384;    // hi-only combined, 28672
    unsigned short* wfc1_f  = wfr + 45056;    // hi/lo stored, hi consumed
    unsigned short* wfc2_f  = wfr + 110592;   // hi/lo stored, hi consumed

    k_pd<<<2744, 256, 0, stream>>>(inp, inpf, xpad, wproj, woff, wmask, wfc1, wfc2,
                                   wfr, dww, dwb, ydwb, psum, psq);
    k_bnstats<<<128, 256, 0, stream>>>(psum, psq, gamma, beta, scs, shs);
    k_bp<<<3072, 256, 0, stream>>>(ydwb, scs, shs, x1f, inpf, wproj_f, bproj, xpad);
    k_fgemm<128, 14, 4, 4, 224, 0, 0><<<dim3(256, 4), 256, 0, stream>>>(x1f, womb_f, boff, (float*)offs, 144, nullptr, bmask, (float*)msk);
    k_dcn<<<1024, 256, 0, stream>>>(xpad, offs, msk, dcnf);
    k_mlp<<<512, 512, 0, stream>>>(dcnf, wfc1_f, bfc1, wfc2_f, bfc2, out);
}

// Round 14
// 91.886 us; speedup vs baseline: 1.2437x; 1.0512x over previous
//
#include <hip/hip_runtime.h>
#include <math.h>

#define NPOS  32768      // B*H*W
#define CDIM  128
#define HS    64
#define WSZ   64

typedef __bf16 bf8_t  __attribute__((ext_vector_type(8)));
typedef float  f32x4  __attribute__((ext_vector_type(4)));

__device__ __forceinline__ float gelu_exact(float x) {
    return 0.5f * x * (1.0f + erff(x * 0.70710678118654752f));
}

__device__ __forceinline__ unsigned short bf16c(float v) {
    return __builtin_bit_cast(unsigned short, (__bf16)v);
}

__device__ __forceinline__ uint4 pack8hi(const float* v) {
    unsigned hh[8];
    #pragma unroll
    for (int i = 0; i < 8; ++i) hh[i] = (unsigned)bf16c(v[i]);
    return make_uint4(hh[0] | (hh[1] << 16), hh[2] | (hh[3] << 16),
                      hh[4] | (hh[5] << 16), hh[6] | (hh[7] << 16));
}

__device__ __forceinline__ float bfd(unsigned u) {        // low 16 bits as bf16
    return __builtin_bit_cast(float, u << 16);
}

// unpack uint4 (8 bf16) and fma into acc[8] with weight
__device__ __forceinline__ void ufma(float* acc, uint4 c, float wgt) {
    const unsigned* cc = (const unsigned*)&c;
    #pragma unroll
    for (int j = 0; j < 4; ++j) {
        acc[2 * j]     += __builtin_bit_cast(float, cc[j] << 16) * wgt;
        acc[2 * j + 1] += __builtin_bit_cast(float, cc[j] & 0xFFFF0000u) * wgt;
    }
}

// ---------------------------------------------------------------------------
// A-frag layouts (K=KC*32):
//  hi-only buffers: block(rt,kc) = 512 ush
//  elem: lane*8 + i, lane = (row%16) + ((k%32)/8)*16, i = k%8
// ---------------------------------------------------------------------------

// ---------------------------------------------------------------------------
// prep body: blocks [0,130) border: zero 1-px ring of bf16 xpad
//            [130,184) wprep: weights -> frag bf16
// (aprep folded into dwconv center tap)
// ---------------------------------------------------------------------------
__device__ void prep_body(
    int bid, int tid,
    unsigned short* __restrict__ xpad,
    const float* __restrict__ w0, const float* __restrict__ w1,
    const float* __restrict__ w2, const float* __restrict__ w3,
    const float* __restrict__ w4, unsigned short* __restrict__ wb)
{
    if (bid < 130) {
        int idx = bid * 256 + tid;         // 2080 cells * 16
        if (idx < 33280) {
            int c8 = (idx & 15) * 8;
            int cell = idx >> 4;
            int b = cell / 260, r = cell % 260;
            int h, w;
            if (r < 66)       { h = 0;  w = r; }
            else if (r < 132) { h = 65; w = r - 66; }
            else { int rr = r - 132; h = 1 + (rr >> 1); w = (rr & 1) * 65; }
            size_t o = (((size_t)b * 66 + h) * 66 + w) * 128 + c8;
            *(uint4*)(xpad + o) = make_uint4(0u, 0u, 0u, 0u);
        }
    } else {
        int sub = (bid - 130) * 4 + (tid >> 6);    // 0..215
        int lane = tid & 63;
        int NT, K, local; unsigned short* out; bool hl; bool comb = false;
        const float* W = nullptr; int N = 0;
        if (sub < 32)       { NT = 8;  K = 128; out = wb;          local = sub;       hl = false; W = w0; N = 128; }
        else if (sub < 88)  { NT = 14; K = 128; out = wb + 16384;  local = sub - 32;  hl = false; comb = true; }
        else if (sub < 152) { NT = 16; K = 128; out = wb + 45056;  local = sub - 88;  hl = true;  W = w3; N = 256; }
        else                { NT = 8;  K = 256; out = wb + 110592; local = sub - 152; hl = true;  W = w4; N = 128; }
        int KC = K / 32;
        int unit = KC * NT * 512;
        int kc = local / NT, t = local % NT;
        int nt = t * 16 + (lane & 15);
        const float* Wp = W; int n = nt, Nv = N;
        if (comb) {
            if (t < 9) { Wp = w1; n = nt;       Nv = 144; }
            else       { Wp = w2; n = nt - 144; Nv = 72;  }
        }
        int kb = kc * 32 + (lane >> 4) * 8;
        size_t base = ((size_t)local * 64 + lane) * 8;
        #pragma unroll
        for (int i = 0; i < 8; ++i) {
            float v = (n < Nv) ? Wp[(size_t)n * K + kb + i] : 0.f;
            __bf16 h = (__bf16)v;
            out[base + i] = __builtin_bit_cast(unsigned short, h);
            if (hl) {
                __bf16 l = (__bf16)(v - (float)h);
                out[unit + base + i] = __builtin_bit_cast(unsigned short, l);
            }
        }
    }
}

// ---------------------------------------------------------------------------
// dwconv body: depthwise 3x3 (NHWC) -> bf16 ydw + partial BN sums (fp32)
//              + center-tap -> inpf hi-only frags (folded aprep)
// ---------------------------------------------------------------------------
__device__ void dwconv_body(
    int blk, int tid,
    const float* __restrict__ inp, const float* __restrict__ dww,
    const float* __restrict__ dwb, unsigned short* __restrict__ ydwb,
    float* __restrict__ psum, float* __restrict__ psq,
    unsigned short* __restrict__ inpf)
{
    int b = blk >> 6, h = blk & 63;
    int c4 = (tid & 31) * 4;
    int wg = tid >> 5;               // 0..7

    float wreg[4][9];
    #pragma unroll
    for (int cc = 0; cc < 4; ++cc)
        #pragma unroll
        for (int p = 0; p < 9; ++p)
            wreg[cc][p] = dww[(c4 + cc) * 9 + p];
    float bia[4];
    #pragma unroll
    for (int cc = 0; cc < 4; ++cc) bia[cc] = dwb[c4 + cc];

    float s4[4] = {0,0,0,0}, q4[4] = {0,0,0,0};
    const float* ibase = inp + (size_t)(b << 12) * CDIM;

    for (int i = 0; i < 8; ++i) {
        int w = wg + i * 8;
        float acc[4] = {bia[0], bia[1], bia[2], bia[3]};
        float4 ctr;
        #pragma unroll
        for (int ky = 0; ky < 3; ++ky) {
            int yy = h + ky - 1;
            if (yy < 0 || yy >= HS) continue;
            #pragma unroll
            for (int kx = 0; kx < 3; ++kx) {
                int xx = w + kx - 1;
                if (xx < 0 || xx >= WSZ) continue;
                float4 v = *(const float4*)(ibase + (size_t)(yy * 64 + xx) * CDIM + c4);
                if (ky == 1 && kx == 1) ctr = v;
                int p = ky * 3 + kx;
                acc[0] += v.x * wreg[0][p];
                acc[1] += v.y * wreg[1][p];
                acc[2] += v.z * wreg[2][p];
                acc[3] += v.w * wreg[3][p];
            }
        }
        int r = (b << 12) + h * 64 + w;
        ushort4 o;
        o.x = bf16c(acc[0]); o.y = bf16c(acc[1]);
        o.z = bf16c(acc[2]); o.w = bf16c(acc[3]);
        *(ushort4*)(ydwb + (size_t)r * CDIM + c4) = o;
        // folded aprep: center tap -> inpf hi-only frag (4 channels)
        {
            int rt = r >> 4, kc = c4 >> 5;
            int lp = (r & 15) + ((c4 & 31) >> 3) * 16;
            int i0 = c4 & 7;
            unsigned u0 = (unsigned)bf16c(ctr.x) | ((unsigned)bf16c(ctr.y) << 16);
            unsigned u1 = (unsigned)bf16c(ctr.z) | ((unsigned)bf16c(ctr.w) << 16);
            *(uint2*)(inpf + ((size_t)rt * 4 + kc) * 512 + lp * 8 + i0) = make_uint2(u0, u1);
        }
        #pragma unroll
        for (int cc = 0; cc < 4; ++cc) { s4[cc] += acc[cc]; q4[cc] += acc[cc] * acc[cc]; }
    }

    __shared__ float ls[8][128], lq[8][128];
    #pragma unroll
    for (int cc = 0; cc < 4; ++cc) { ls[wg][c4 + cc] = s4[cc]; lq[wg][c4 + cc] = q4[cc]; }
    __syncthreads();
    if (tid < 128) {
        float s = 0.f, q = 0.f;
        #pragma unroll
        for (int r = 0; r < 8; ++r) { s += ls[r][tid]; q += lq[r][tid]; }
        psum[blk * 128 + tid] = s;
        psq [blk * 128 + tid] = q;
    }
}

// K_pd: merged prep (184 blocks) + dwconv (512 blocks). grid 696.
__global__ __launch_bounds__(256) void k_pd(
    const float* __restrict__ inp, unsigned short* __restrict__ inpf,
    unsigned short* __restrict__ xpad,
    const float* __restrict__ w0, const float* __restrict__ w1,
    const float* __restrict__ w2, const float* __restrict__ w3,
    const float* __restrict__ w4, unsigned short* __restrict__ wb,
    const float* __restrict__ dww, const float* __restrict__ dwb,
    unsigned short* __restrict__ ydwb, float* __restrict__ psum,
    float* __restrict__ psq)
{
    int bid = blockIdx.x;
    if (bid < 184) prep_body(bid, threadIdx.x, xpad, w0, w1, w2, w3, w4, wb);
    else           dwconv_body(bid - 184, threadIdx.x, inp, dww, dwb, ydwb, psum, psq, inpf);
}

// ---------------------------------------------------------------------------
// K2: finalize BN stats -> scale/shift per channel.
// ---------------------------------------------------------------------------
__global__ __launch_bounds__(256) void k_bnstats(
    const float* __restrict__ psum, const float* __restrict__ psq,
    const float* __restrict__ gamma, const float* __restrict__ beta,
    float* __restrict__ sc, float* __restrict__ sh)
{
    int c = blockIdx.x;
    int t = threadIdx.x;
    float s = psum[t * 128 + c] + psum[(t + 256) * 128 + c];
    float q = psq [t * 128 + c] + psq [(t + 256) * 128 + c];
    __shared__ float rs[256], rq[256];
    rs[t] = s; rq[t] = q; __syncthreads();
    for (int off = 128; off > 0; off >>= 1) {
        if (t < off) { rs[t] += rs[t + off]; rq[t] += rq[t + off]; }
        __syncthreads();
    }
    if (t == 0) {
        float mean = rs[0] * (1.0f / 32768.0f);
        float var  = rq[0] * (1.0f / 32768.0f) - mean * mean;
        float scale = gamma[c] * rsqrtf(var + 1e-5f);
        sc[c] = scale;
        sh[c] = beta[c] - mean * scale;
    }
}

// ---------------------------------------------------------------------------
// bngelu body: bf16 ydw -> BN + exact GELU -> x1 hi-only frags.
// ---------------------------------------------------------------------------
__device__ void bngelu_body(
    int bid, int tid,
    const unsigned short* __restrict__ ydwb, const float* __restrict__ sc,
    const float* __restrict__ sh, unsigned short* __restrict__ dst)
{
    int idx = bid * 256 + tid;   // 32768*16
    int r = idx >> 4, k8 = (idx & 15) * 8;
    uint4 yv = *(const uint4*)(ydwb + (size_t)r * 128 + k8);
    const unsigned* cc = (const unsigned*)&yv;
    float t[8];
    #pragma unroll
    for (int j = 0; j < 4; ++j) {
        t[2 * j]     = bfd(cc[j]);
        t[2 * j + 1] = __builtin_bit_cast(float, cc[j] & 0xFFFF0000u);
    }
    float s[8], h[8];
    *(float4*)(s)     = *(const float4*)(sc + k8);
    *(float4*)(s + 4) = *(const float4*)(sc + k8 + 4);
    *(float4*)(h)     = *(const float4*)(sh + k8);
    *(float4*)(h + 4) = *(const float4*)(sh + k8 + 4);
    #pragma unroll
    for (int i = 0; i < 8; ++i) t[i] = gelu_exact(t[i] * s[i] + h[i]);
    uint4 hi = pack8hi(t);
    int rt = r >> 4, kc = k8 >> 5, lp = (r & 15) + ((k8 & 31) >> 3) * 16;
    size_t base = ((size_t)rt * 4 + kc) * 512 + lp * 8;
    *(uint4*)(dst + base) = hi;
}

// ---------------------------------------------------------------------------
// Frag-stream MFMA GEMM body.
// MODE 3: bf16 padded [b][66][66][128] store.
// MODE 4: bf16 split store: tiles 0..8 -> offs (ld 144), 9..13 -> msk (ld 72).
// A and W hi-only here.
// ---------------------------------------------------------------------------
template<int KDIM, int NT_TOT, int NT_W, int MODE, int NV>
__device__ void fgemm_body(
    int bx, int by, int tid,
    const unsigned short* __restrict__ AF, const unsigned short* __restrict__ WF,
    const float* __restrict__ bias, float* __restrict__ C,
    const float* __restrict__ bias2, float* __restrict__ C2)
{
    constexpr int KC = KDIM / 32;
    int lane = tid & 63, w = tid >> 6;
    int rt0 = bx * 8 + w * 2;      // 2 rowtiles per wave
    int t0 = by * NT_W;            // n-tile chunk base

    f32x4 acc[2][NT_W];
    #pragma unroll
    for (int rt = 0; rt < 2; ++rt)
        #pragma unroll
        for (int t = 0; t < NT_W; ++t) acc[rt][t] = (f32x4){0.f, 0.f, 0.f, 0.f};

    const bf8_t* Ab0 = (const bf8_t*)AF + (size_t)rt0 * KC * 64 + lane;
    const bf8_t* Ab1 = Ab0 + KC * 64;
    const bf8_t* WHp = (const bf8_t*)WF + lane;

    #pragma unroll
    for (int kc = 0; kc < KC; ++kc) {
        bf8_t a0h = Ab0[kc * 64];
        bf8_t a1h = Ab1[kc * 64];
        #pragma unroll
        for (int t = 0; t < NT_W; ++t) {
            int tg = t0 + t;
            if (tg < NT_TOT) {
                bf8_t wh = WHp[(kc * NT_TOT + tg) * 64];
                acc[0][t] = __builtin_amdgcn_mfma_f32_16x16x32_bf16(wh, a0h, acc[0][t], 0, 0, 0);
                acc[1][t] = __builtin_amdgcn_mfma_f32_16x16x32_bf16(wh, a1h, acc[1][t], 0, 0, 0);
            }
        }
    }

    #pragma unroll
    for (int rt = 0; rt < 2; ++rt) {
        if (MODE == 3) {
            // bf16 store into zero-padded [b][66][66][128]
            unsigned short* Cp = (unsigned short*)C;
            int m = (rt0 + rt) * 16 + (lane & 15);
            int bb_ = m >> 12, hwm = m & 4095;
            size_t rowb = (((size_t)bb_ * 66 + (hwm >> 6) + 1) * 66 + (hwm & 63) + 1) * 128;
            #pragma unroll
            for (int t = 0; t < NT_W; ++t) {
                int tg = t0 + t;
                int nb = tg * 16 + ((lane >> 4) << 2);
                if (tg < NT_TOT) {
                    float4 bb = *(const float4*)(bias + nb);
                    f32x4 a = acc[rt][t];
                    ushort4 v;
                    v.x = bf16c(a[0] + bb.x); v.y = bf16c(a[1] + bb.y);
                    v.z = bf16c(a[2] + bb.z); v.w = bf16c(a[3] + bb.w);
                    *(ushort4*)(Cp + rowb + nb) = v;
                }
            }
        } else if (MODE == 4) {
            // bf16 split store: offs (C, ld 144) and msk (C2, ld 72)
            unsigned short* Co = (unsigned short*)C;
            unsigned short* Cm = (unsigned short*)C2;
            int m = (rt0 + rt) * 16 + (lane & 15);
            #pragma unroll
            for (int t = 0; t < NT_W; ++t) {
                int tg = t0 + t;
                if (tg < NT_TOT) {
                    int nb = tg * 16 + ((lane >> 4) << 2);
                    f32x4 a = acc[rt][t];
                    if (nb < 144) {
                        float4 bb = *(const float4*)(bias + nb);
                        ushort4 v;
                        v.x = bf16c(a[0] + bb.x); v.y = bf16c(a[1] + bb.y);
                        v.z = bf16c(a[2] + bb.z); v.w = bf16c(a[3] + bb.w);
                        *(ushort4*)(Co + (size_t)m * 144 + nb) = v;
                    } else {
                        int col = nb - 144;
                        if (col + 4 <= 72) {
                            float4 bb = *(const float4*)(bias2 + col);
                            ushort4 v;
                            v.x = bf16c(a[0] + bb.x); v.y = bf16c(a[1] + bb.y);
                            v.z = bf16c(a[2] + bb.z); v.w = bf16c(a[3] + bb.w);
                            *(ushort4*)(Cm + (size_t)m * 72 + col) = v;
                        }
                    }
                }
            }
        }
    }
}

template<int KDIM, int NT_TOT, int NT_W, int MODE, int NV>
__global__ __launch_bounds__(256) void k_fgemm(
    const unsigned short* __restrict__ AF, const unsigned short* __restrict__ WF,
    const float* __restrict__ bias, float* __restrict__ C,
    const float* __restrict__ bias2, float* __restrict__ C2)
{
    fgemm_body<KDIM, NT_TOT, NT_W, MODE, NV>(
        blockIdx.x, blockIdx.y, threadIdx.x, AF, WF, bias, C, bias2, C2);
}

// K_bp: merged bngelu (2048 blocks) + proj GEMM (512 blocks, NT_W=4). grid 2560.
__global__ __launch_bounds__(256) void k_bp(
    const unsigned short* __restrict__ ydwb, const float* __restrict__ sc,
    const float* __restrict__ sh, unsigned short* __restrict__ x1f,
    const unsigned short* __restrict__ inpf, const unsigned short* __restrict__ wprojf,
    const float* __restrict__ bproj, unsigned short* __restrict__ xpad)
{
    int bid = blockIdx.x;
    if (bid < 2048) {
        bngelu_body(bid, threadIdx.x, ydwb, sc, sh, x1f);
    } else {
        int pbid = bid - 2048;
        fgemm_body<128, 8, 4, 3, 128>(pbid & 255, pbid >> 8, threadIdx.x,
            inpf, wprojf, bproj, (float*)xpad, nullptr, nullptr);
    }
}

// ---------------------------------------------------------------------------
// K6: DCNv3 core. thread = (pos, g), 16 channels. grid 1024, block 256.
// ---------------------------------------------------------------------------
__global__ __launch_bounds__(256) void k_dcn(
    const unsigned short* __restrict__ xpad, const unsigned short* __restrict__ offs,
    const unsigned short* __restrict__ msk, unsigned short* __restrict__ dcnf)
{
    int u = blockIdx.x * 256 + threadIdx.x;  // 32768*8
    int g = u & 7;
    int pos = u >> 3;
    int b = pos >> 12, hw = pos & 4095, h = hw >> 6, w = hw & 63;

    const unsigned short* ml = msk + (size_t)pos * 72 + g * 9;
    float e[9];
    float mx = -1e30f;
    #pragma unroll
    for (int p = 0; p < 9; ++p) { e[p] = bfd((unsigned)ml[p]); mx = fmaxf(mx, e[p]); }
    float ssum = 0.f;
    #pragma unroll
    for (int p = 0; p < 9; ++p) { e[p] = __expf(e[p] - mx); ssum += e[p]; }
    float inv = 1.0f / ssum;

    const unsigned short* ob = offs + (size_t)pos * 144 + g * 18;
    const unsigned short* xb = xpad + (size_t)b * 557568 + g * 16;  // 66*66*128/b

    float acc[16];
    #pragma unroll
    for (int i = 0; i < 16; ++i) acc[i] = 0.f;

    #pragma unroll
    for (int p = 0; p < 9; ++p) {
        unsigned dpair = *(const unsigned*)(ob + p * 2);
        float dx = bfd(dpair);
        float dy = __builtin_bit_cast(float, dpair & 0xFFFF0000u);
        float px = (float)(w + (p % 3)) + dx;   // padded-grid coords
        float py = (float)(h + (p / 3)) + dy;
        float x0f = floorf(px), y0f = floorf(py);
        float wx = px - x0f, wy = py - y0f;
        int ix = (int)x0f, iy = (int)y0f;
        int ix0 = max(min(ix, 65), 0),     ix1 = max(min(ix + 1, 65), 0);
        int iy0 = max(min(iy, 65), 0),     iy1 = max(min(iy + 1, 65), 0);
        int r0 = iy0 * 66, r1 = iy1 * 66;

        float mp  = e[p] * inv;
        float w11 = wy * wx * mp;
        float w10 = wy * mp - w11;
        float w01 = wx * mp - w11;
        float w00 = mp - w01 - w10 - w11;

        const unsigned short* c00 = xb + (size_t)(r0 + ix0) * 128;
        const unsigned short* c01 = xb + (size_t)(r0 + ix1) * 128;
        const unsigned short* c10 = xb + (size_t)(r1 + ix0) * 128;
        const unsigned short* c11 = xb + (size_t)(r1 + ix1) * 128;

        uint4 a00 = *(const uint4*)(c00), b00 = *(const uint4*)(c00 + 8);
        uint4 a01 = *(const uint4*)(c01), b01 = *(const uint4*)(c01 + 8);
        uint4 a10 = *(const uint4*)(c10), b10 = *(const uint4*)(c10 + 8);
        uint4 a11 = *(const uint4*)(c11), b11 = *(const uint4*)(c11 + 8);

        ufma(acc,     a00, w00); ufma(acc + 8, b00, w00);
        ufma(acc,     a01, w01); ufma(acc + 8, b01, w01);
        ufma(acc,     a10, w10); ufma(acc + 8, b10, w10);
        ufma(acc,     a11, w11); ufma(acc + 8, b11, w11);
    }

    // pack 16 channels as two hi-only frag groups
    int rt = pos >> 4, kc = g >> 1;
    int lp0 = (pos & 15) + (g & 1) * 32;
    size_t fb = ((size_t)rt * 4 + kc) * 512 + (size_t)lp0 * 8;
    uint4 hiA = pack8hi(acc);
    uint4 hiB = pack8hi(acc + 8);
    *(uint4*)(dcnf + fb)       = hiA;
    *(uint4*)(dcnf + fb + 128) = hiB;   // lp0+16
}

// ---------------------------------------------------------------------------
// K7: fused output MLP. block = 512 threads (8 waves) = 2 rowtile-PAIRS.
// wave w: pr = w&1 (pair), chunk = w>>1 (0..3).
// fc1: 4 hidden tiles x 2 rowtiles, hi-only W -> GELU -> LDS. barrier.
// fc2: 2 out tiles x 2 rowtiles, hi-only W, A from LDS. fp32 NCHW store.
// ---------------------------------------------------------------------------
__global__ __launch_bounds__(512) void k_mlp(
    const unsigned short* __restrict__ dcnf, const unsigned short* __restrict__ wf1,
    const float* __restrict__ bfc1, const unsigned short* __restrict__ wf2,
    const float* __restrict__ bfc2, float* __restrict__ out)
{
    __shared__ unsigned short hid[4][16][264];   // 4 rowtiles, 33.8 KB
    int tid = threadIdx.x;
    int lane = tid & 63, w = tid >> 6;           // 8 waves
    int pr = w & 1, chunk = w >> 1;              // pair-local, chunk 0..3
    int bp = blockIdx.x * 2 + pr;                // pair id 0..1023
    int rt0 = bp * 2;                            // rowtiles rt0, rt0+1
    int m = lane & 15, hi4 = (lane >> 4) << 2;

    // ---- fc1: hidden tiles chunk*4 .. +3, rowtiles rt0, rt0+1 ----
    f32x4 acc[2][4];
    #pragma unroll
    for (int r = 0; r < 2; ++r)
        #pragma unroll
        for (int t = 0; t < 4; ++t) acc[r][t] = (f32x4){0.f, 0.f, 0.f, 0.f};
    const bf8_t* Ab0 = (const bf8_t*)dcnf + (size_t)rt0 * 4 * 64 + lane;  // KC=4 hi-only
    const bf8_t* Ab1 = Ab0 + 4 * 64;
    const bf8_t* WH1 = (const bf8_t*)wf1 + lane;
    #pragma unroll
    for (int kc = 0; kc < 4; ++kc) {
        bf8_t a0 = Ab0[kc * 64];
        bf8_t a1 = Ab1[kc * 64];
        #pragma unroll
        for (int t = 0; t < 4; ++t) {
            int tg = chunk * 4 + t;
            bf8_t wh = WH1[(kc * 16 + tg) * 64];
            acc[0][t] = __builtin_amdgcn_mfma_f32_16x16x32_bf16(wh, a0, acc[0][t], 0, 0, 0);
            acc[1][t] = __builtin_amdgcn_mfma_f32_16x16x32_bf16(wh, a1, acc[1][t], 0, 0, 0);
        }
    }
    // GELU + bf16 -> LDS (lane holds row m, n = tg*16+hi4..+3)
    #pragma unroll
    for (int r = 0; r < 2; ++r) {
        #pragma unroll
        for (int t = 0; t < 4; ++t) {
            int nb = (chunk * 4 + t) * 16 + hi4;
            float4 bb = *(const float4*)(bfc1 + nb);
            ushort4 v;
            v.x = bf16c(gelu_exact(acc[r][t][0] + bb.x));
            v.y = bf16c(gelu_exact(acc[r][t][1] + bb.y));
            v.z = bf16c(gelu_exact(acc[r][t][2] + bb.z));
            v.w = bf16c(gelu_exact(acc[r][t][3] + bb.w));
            *(ushort4*)(&hid[pr * 2 + r][m][nb]) = v;
        }
    }

    __syncthreads();

    // ---- fc2: out tiles chunk*2 .. +1, rowtiles rt0, rt0+1 ----
    f32x4 acc2[2][2];
    #pragma unroll
    for (int r = 0; r < 2; ++r)
        #pragma unroll
        for (int t = 0; t < 2; ++t) acc2[r][t] = (f32x4){0.f, 0.f, 0.f, 0.f};
    const bf8_t* WH2 = (const bf8_t*)wf2 + lane;
    #pragma unroll
    for (int kc = 0; kc < 8; ++kc) {
        bf8_t ah0 = *(const bf8_t*)(&hid[pr * 2 + 0][m][kc * 32 + (lane >> 4) * 8]);
        bf8_t ah1 = *(const bf8_t*)(&hid[pr * 2 + 1][m][kc * 32 + (lane >> 4) * 8]);
        #pragma unroll
        for (int t = 0; t < 2; ++t) {
            int tg = chunk * 2 + t;
            bf8_t wh = WH2[(kc * 8 + tg) * 64];
            acc2[0][t] = __builtin_amdgcn_mfma_f32_16x16x32_bf16(ah0, wh, acc2[0][t], 0, 0, 0);
            acc2[1][t] = __builtin_amdgcn_mfma_f32_16x16x32_bf16(ah1, wh, acc2[1][t], 0, 0, 0);
        }
    }
    // NCHW transposed fp32 store
    #pragma unroll
    for (int r = 0; r < 2; ++r) {
        int m4 = (rt0 + r) * 16 + hi4;
        int b = m4 >> 12, hw = m4 & 4095;
        #pragma unroll
        for (int t = 0; t < 2; ++t) {
            int n = (chunk * 2 + t) * 16 + m;
            float bb = bfc2[n];
            f32x4 a = acc2[r][t];
            float4 v = {a[0] + bb, a[1] + bb, a[2] + bb, a[3] + bb};
            *(float4*)(out + (((size_t)(b * 128 + n)) << 12) + hw) = v;
        }
    }
}

// ---------------------------------------------------------------------------
extern "C" void kernel_launch(void* const* d_in, const int* in_sizes, int n_in,
                              void* d_out, int out_size, void* d_ws, size_t ws_size,
                              hipStream_t stream)
{
    const float* inp   = (const float*)d_in[0];
    const float* wproj = (const float*)d_in[1];
    const float* bproj = (const float*)d_in[2];
    const float* dww   = (const float*)d_in[3];
    const float* dwb   = (const float*)d_in[4];
    const float* gamma = (const float*)d_in[5];
    const float* beta  = (const float*)d_in[6];
    const float* woff  = (const float*)d_in[7];
    const float* boff  = (const float*)d_in[8];
    const float* wmask = (const float*)d_in[9];
    const float* bmask = (const float*)d_in[10];
    const float* wfc1  = (const float*)d_in[11];
    const float* bfc1  = (const float*)d_in[12];
    const float* wfc2  = (const float*)d_in[13];
    const float* bfc2  = (const float*)d_in[14];
    float* out = (float*)d_out;
    float* ws  = (float*)d_ws;

    // Region P: xpad (bf16) + offs (bf16)
    unsigned short* xpad = (unsigned short*)ws;              // 4,460,544 ush [proj..dcn]
    unsigned short* offs = (unsigned short*)(ws + 2230272);  // 4,718,592 ush [offmask..dcn]
    // Region A at ws+9179136: inpf [pd..bp-proj], dcnf [dcn..mlp]
    unsigned short* inpf  = (unsigned short*)(ws + 9179136);   // 4,194,304 ush hi-only
    unsigned short* dcnf  = (unsigned short*)(ws + 9179136);   // 4,194,304 ush hi-only
    unsigned short* x1f   = (unsigned short*)(ws + 13373440);  // 4,194,304 ush hi-only [bp..offmask]
    unsigned short* ydwb  = (unsigned short*)(ws + 15470592);  // 4,194,304 ush bf16 [pd..bp]
    // Rest
    unsigned short* msk = (unsigned short*)(ws + 17567744);  // 2,359,296 ush
    float* psum = ws + 19927040;                         // 65,536 f
    float* psq  = ws + 19992576;                         // 65,536 f
    float* scs  = ws + 20058112;                         // 128 f
    float* shs  = ws + 20058240;                         // 128 f
    unsigned short* wfr = (unsigned short*)(ws + 20058368);  // 176,128 ush

    unsigned short* wproj_f = wfr;            // hi-only, 16384
    unsigned short* womb_f  = wfr + 16384;    // hi-only combined, 28672
    unsigned short* wfc1_f  = wfr + 45056;    // hi/lo stored, hi consumed
    unsigned short* wfc2_f  = wfr + 110592;   // hi/lo stored, hi consumed

    k_pd<<<696, 256, 0, stream>>>(inp, inpf, xpad, wproj, woff, wmask, wfc1, wfc2,
                                  wfr, dww, dwb, ydwb, psum, psq);
    k_bnstats<<<128, 256, 0, stream>>>(psum, psq, gamma, beta, scs, shs);
    k_bp<<<2560, 256, 0, stream>>>(ydwb, scs, shs, x1f, inpf, wproj_f, bproj, xpad);
    k_fgemm<128, 14, 4, 4, 224><<<dim3(256, 4), 256, 0, stream>>>(x1f, womb_f, boff, (float*)offs, bmask, (float*)msk);
    k_dcn<<<1024, 256, 0, stream>>>(xpad, offs, msk, dcnf);
    k_mlp<<<512, 512, 0, stream>>>(dcnf, wfc1_f, bfc1, wfc2_f, bfc2, out);
}

// Round 15
// 85.946 us; speedup vs baseline: 1.3297x; 1.0691x over previous
//
#include <hip/hip_runtime.h>
#include <math.h>

#define NPOS  32768      // B*H*W
#define CDIM  128
#define HS    64
#define WSZ   64

typedef __bf16 bf8_t  __attribute__((ext_vector_type(8)));
typedef float  f32x4  __attribute__((ext_vector_type(4)));

__device__ __forceinline__ float gelu_exact(float x) {
    return 0.5f * x * (1.0f + erff(x * 0.70710678118654752f));
}

__device__ __forceinline__ unsigned short bf16c(float v) {
    return __builtin_bit_cast(unsigned short, (__bf16)v);
}

__device__ __forceinline__ uint4 pack8hi(const float* v) {
    unsigned hh[8];
    #pragma unroll
    for (int i = 0; i < 8; ++i) hh[i] = (unsigned)bf16c(v[i]);
    return make_uint4(hh[0] | (hh[1] << 16), hh[2] | (hh[3] << 16),
                      hh[4] | (hh[5] << 16), hh[6] | (hh[7] << 16));
}

__device__ __forceinline__ float bfd(unsigned u) {        // low 16 bits as bf16
    return __builtin_bit_cast(float, u << 16);
}

// unpack uint4 (8 bf16) and fma into acc[8] with weight
__device__ __forceinline__ void ufma(float* acc, uint4 c, float wgt) {
    const unsigned* cc = (const unsigned*)&c;
    #pragma unroll
    for (int j = 0; j < 4; ++j) {
        acc[2 * j]     += __builtin_bit_cast(float, cc[j] << 16) * wgt;
        acc[2 * j + 1] += __builtin_bit_cast(float, cc[j] & 0xFFFF0000u) * wgt;
    }
}

// ---------------------------------------------------------------------------
// A-frag layouts (K=KC*32): hi-only buffers: block(rt,kc) = 512 ush
//  elem: lane*8 + i, lane = (row%16) + ((k%32)/8)*16, i = k%8
// ---------------------------------------------------------------------------

// ---------------------------------------------------------------------------
// prep body: blocks [0,130) border: zero 1-px ring of bf16 xpad
//            [130,184) wprep: weights -> frag bf16
// ---------------------------------------------------------------------------
__device__ void prep_body(
    int bid, int tid,
    unsigned short* __restrict__ xpad,
    const float* __restrict__ w0, const float* __restrict__ w1,
    const float* __restrict__ w2, const float* __restrict__ w3,
    const float* __restrict__ w4, unsigned short* __restrict__ wb)
{
    if (bid < 130) {
        int idx = bid * 256 + tid;         // 2080 cells * 16
        if (idx < 33280) {
            int c8 = (idx & 15) * 8;
            int cell = idx >> 4;
            int b = cell / 260, r = cell % 260;
            int h, w;
            if (r < 66)       { h = 0;  w = r; }
            else if (r < 132) { h = 65; w = r - 66; }
            else { int rr = r - 132; h = 1 + (rr >> 1); w = (rr & 1) * 65; }
            size_t o = (((size_t)b * 66 + h) * 66 + w) * 128 + c8;
            *(uint4*)(xpad + o) = make_uint4(0u, 0u, 0u, 0u);
        }
    } else {
        int sub = (bid - 130) * 4 + (tid >> 6);    // 0..215
        int lane = tid & 63;
        int NT, K, local; unsigned short* out; bool hl; bool comb = false;
        const float* W = nullptr; int N = 0;
        if (sub < 32)       { NT = 8;  K = 128; out = wb;          local = sub;       hl = false; W = w0; N = 128; }
        else if (sub < 88)  { NT = 14; K = 128; out = wb + 16384;  local = sub - 32;  hl = false; comb = true; }
        else if (sub < 152) { NT = 16; K = 128; out = wb + 45056;  local = sub - 88;  hl = true;  W = w3; N = 256; }
        else                { NT = 8;  K = 256; out = wb + 110592; local = sub - 152; hl = true;  W = w4; N = 128; }
        int KC = K / 32;
        int unit = KC * NT * 512;
        int kc = local / NT, t = local % NT;
        int nt = t * 16 + (lane & 15);
        const float* Wp = W; int n = nt, Nv = N;
        if (comb) {
            if (t < 9) { Wp = w1; n = nt;       Nv = 144; }
            else       { Wp = w2; n = nt - 144; Nv = 72;  }
        }
        int kb = kc * 32 + (lane >> 4) * 8;
        size_t base = ((size_t)local * 64 + lane) * 8;
        #pragma unroll
        for (int i = 0; i < 8; ++i) {
            float v = (n < Nv) ? Wp[(size_t)n * K + kb + i] : 0.f;
            __bf16 h = (__bf16)v;
            out[base + i] = __builtin_bit_cast(unsigned short, h);
            if (hl) {
                __bf16 l = (__bf16)(v - (float)h);
                out[unit + base + i] = __builtin_bit_cast(unsigned short, l);
            }
        }
    }
}

// ---------------------------------------------------------------------------
// dwconv body: depthwise 3x3 (NHWC) -> bf16 ydw + partial BN sums (fp32)
//              + center-tap -> inpf hi-only frags (folded aprep)
// ---------------------------------------------------------------------------
__device__ void dwconv_body(
    int blk, int tid,
    const float* __restrict__ inp, const float* __restrict__ dww,
    const float* __restrict__ dwb, unsigned short* __restrict__ ydwb,
    float* __restrict__ psum, float* __restrict__ psq,
    unsigned short* __restrict__ inpf)
{
    int b = blk >> 6, h = blk & 63;
    int c4 = (tid & 31) * 4;
    int wg = tid >> 5;               // 0..7

    float wreg[4][9];
    #pragma unroll
    for (int cc = 0; cc < 4; ++cc)
        #pragma unroll
        for (int p = 0; p < 9; ++p)
            wreg[cc][p] = dww[(c4 + cc) * 9 + p];
    float bia[4];
    #pragma unroll
    for (int cc = 0; cc < 4; ++cc) bia[cc] = dwb[c4 + cc];

    float s4[4] = {0,0,0,0}, q4[4] = {0,0,0,0};
    const float* ibase = inp + (size_t)(b << 12) * CDIM;

    for (int i = 0; i < 8; ++i) {
        int w = wg + i * 8;
        float acc[4] = {bia[0], bia[1], bia[2], bia[3]};
        float4 ctr;
        #pragma unroll
        for (int ky = 0; ky < 3; ++ky) {
            int yy = h + ky - 1;
            if (yy < 0 || yy >= HS) continue;
            #pragma unroll
            for (int kx = 0; kx < 3; ++kx) {
                int xx = w + kx - 1;
                if (xx < 0 || xx >= WSZ) continue;
                float4 v = *(const float4*)(ibase + (size_t)(yy * 64 + xx) * CDIM + c4);
                if (ky == 1 && kx == 1) ctr = v;
                int p = ky * 3 + kx;
                acc[0] += v.x * wreg[0][p];
                acc[1] += v.y * wreg[1][p];
                acc[2] += v.z * wreg[2][p];
                acc[3] += v.w * wreg[3][p];
            }
        }
        int r = (b << 12) + h * 64 + w;
        ushort4 o;
        o.x = bf16c(acc[0]); o.y = bf16c(acc[1]);
        o.z = bf16c(acc[2]); o.w = bf16c(acc[3]);
        *(ushort4*)(ydwb + (size_t)r * CDIM + c4) = o;
        // folded aprep: center tap -> inpf hi-only frag (4 channels)
        {
            int rt = r >> 4, kc = c4 >> 5;
            int lp = (r & 15) + ((c4 & 31) >> 3) * 16;
            int i0 = c4 & 7;
            unsigned u0 = (unsigned)bf16c(ctr.x) | ((unsigned)bf16c(ctr.y) << 16);
            unsigned u1 = (unsigned)bf16c(ctr.z) | ((unsigned)bf16c(ctr.w) << 16);
            *(uint2*)(inpf + ((size_t)rt * 4 + kc) * 512 + lp * 8 + i0) = make_uint2(u0, u1);
        }
        #pragma unroll
        for (int cc = 0; cc < 4; ++cc) { s4[cc] += acc[cc]; q4[cc] += acc[cc] * acc[cc]; }
    }

    __shared__ float ls[8][128], lq[8][128];
    #pragma unroll
    for (int cc = 0; cc < 4; ++cc) { ls[wg][c4 + cc] = s4[cc]; lq[wg][c4 + cc] = q4[cc]; }
    __syncthreads();
    if (tid < 128) {
        float s = 0.f, q = 0.f;
        #pragma unroll
        for (int r = 0; r < 8; ++r) { s += ls[r][tid]; q += lq[r][tid]; }
        psum[blk * 128 + tid] = s;
        psq [blk * 128 + tid] = q;
    }
}

// K_pd: merged prep (184 blocks) + dwconv (512 blocks). grid 696.
__global__ __launch_bounds__(256) void k_pd(
    const float* __restrict__ inp, unsigned short* __restrict__ inpf,
    unsigned short* __restrict__ xpad,
    const float* __restrict__ w0, const float* __restrict__ w1,
    const float* __restrict__ w2, const float* __restrict__ w3,
    const float* __restrict__ w4, unsigned short* __restrict__ wb,
    const float* __restrict__ dww, const float* __restrict__ dwb,
    unsigned short* __restrict__ ydwb, float* __restrict__ psum,
    float* __restrict__ psq)
{
    int bid = blockIdx.x;
    if (bid < 184) prep_body(bid, threadIdx.x, xpad, w0, w1, w2, w3, w4, wb);
    else           dwconv_body(bid - 184, threadIdx.x, inp, dww, dwb, ydwb, psum, psq, inpf);
}

// ---------------------------------------------------------------------------
// K2: finalize BN stats -> scale/shift per channel.
// ---------------------------------------------------------------------------
__global__ __launch_bounds__(256) void k_bnstats(
    const float* __restrict__ psum, const float* __restrict__ psq,
    const float* __restrict__ gamma, const float* __restrict__ beta,
    float* __restrict__ sc, float* __restrict__ sh)
{
    int c = blockIdx.x;
    int t = threadIdx.x;
    float s = psum[t * 128 + c] + psum[(t + 256) * 128 + c];
    float q = psq [t * 128 + c] + psq [(t + 256) * 128 + c];
    __shared__ float rs[256], rq[256];
    rs[t] = s; rq[t] = q; __syncthreads();
    for (int off = 128; off > 0; off >>= 1) {
        if (t < off) { rs[t] += rs[t + off]; rq[t] += rq[t + off]; }
        __syncthreads();
    }
    if (t == 0) {
        float mean = rs[0] * (1.0f / 32768.0f);
        float var  = rq[0] * (1.0f / 32768.0f) - mean * mean;
        float scale = gamma[c] * rsqrtf(var + 1e-5f);
        sc[c] = scale;
        sh[c] = beta[c] - mean * scale;
    }
}

// ---------------------------------------------------------------------------
// bngelu body: bf16 ydw -> BN + exact GELU -> x1 hi-only frags.
// ---------------------------------------------------------------------------
__device__ void bngelu_body(
    int bid, int tid,
    const unsigned short* __restrict__ ydwb, const float* __restrict__ sc,
    const float* __restrict__ sh, unsigned short* __restrict__ dst)
{
    int idx = bid * 256 + tid;   // 32768*16
    int r = idx >> 4, k8 = (idx & 15) * 8;
    uint4 yv = *(const uint4*)(ydwb + (size_t)r * 128 + k8);
    const unsigned* cc = (const unsigned*)&yv;
    float t[8];
    #pragma unroll
    for (int j = 0; j < 4; ++j) {
        t[2 * j]     = bfd(cc[j]);
        t[2 * j + 1] = __builtin_bit_cast(float, cc[j] & 0xFFFF0000u);
    }
    float s[8], h[8];
    *(float4*)(s)     = *(const float4*)(sc + k8);
    *(float4*)(s + 4) = *(const float4*)(sc + k8 + 4);
    *(float4*)(h)     = *(const float4*)(sh + k8);
    *(float4*)(h + 4) = *(const float4*)(sh + k8 + 4);
    #pragma unroll
    for (int i = 0; i < 8; ++i) t[i] = gelu_exact(t[i] * s[i] + h[i]);
    uint4 hi = pack8hi(t);
    int rt = r >> 4, kc = k8 >> 5, lp = (r & 15) + ((k8 & 31) >> 3) * 16;
    size_t base = ((size_t)rt * 4 + kc) * 512 + lp * 8;
    *(uint4*)(dst + base) = hi;
}

// ---------------------------------------------------------------------------
// Frag-stream MFMA GEMM body (hi-only). MODE 3: bf16 padded store.
// ---------------------------------------------------------------------------
template<int KDIM, int NT_TOT, int NT_W, int MODE, int NV>
__device__ void fgemm_body(
    int bx, int by, int tid,
    const unsigned short* __restrict__ AF, const unsigned short* __restrict__ WF,
    const float* __restrict__ bias, float* __restrict__ C)
{
    constexpr int KC = KDIM / 32;
    int lane = tid & 63, w = tid >> 6;
    int rt0 = bx * 8 + w * 2;      // 2 rowtiles per wave
    int t0 = by * NT_W;            // n-tile chunk base

    f32x4 acc[2][NT_W];
    #pragma unroll
    for (int rt = 0; rt < 2; ++rt)
        #pragma unroll
        for (int t = 0; t < NT_W; ++t) acc[rt][t] = (f32x4){0.f, 0.f, 0.f, 0.f};

    const bf8_t* Ab0 = (const bf8_t*)AF + (size_t)rt0 * KC * 64 + lane;
    const bf8_t* Ab1 = Ab0 + KC * 64;
    const bf8_t* WHp = (const bf8_t*)WF + lane;

    #pragma unroll
    for (int kc = 0; kc < KC; ++kc) {
        bf8_t a0h = Ab0[kc * 64];
        bf8_t a1h = Ab1[kc * 64];
        #pragma unroll
        for (int t = 0; t < NT_W; ++t) {
            int tg = t0 + t;
            if (tg < NT_TOT) {
                bf8_t wh = WHp[(kc * NT_TOT + tg) * 64];
                acc[0][t] = __builtin_amdgcn_mfma_f32_16x16x32_bf16(wh, a0h, acc[0][t], 0, 0, 0);
                acc[1][t] = __builtin_amdgcn_mfma_f32_16x16x32_bf16(wh, a1h, acc[1][t], 0, 0, 0);
            }
        }
    }

    #pragma unroll
    for (int rt = 0; rt < 2; ++rt) {
        if (MODE == 3) {
            unsigned short* Cp = (unsigned short*)C;
            int m = (rt0 + rt) * 16 + (lane & 15);
            int bb_ = m >> 12, hwm = m & 4095;
            size_t rowb = (((size_t)bb_ * 66 + (hwm >> 6) + 1) * 66 + (hwm & 63) + 1) * 128;
            #pragma unroll
            for (int t = 0; t < NT_W; ++t) {
                int tg = t0 + t;
                int nb = tg * 16 + ((lane >> 4) << 2);
                if (tg < NT_TOT) {
                    float4 bb = *(const float4*)(bias + nb);
                    f32x4 a = acc[rt][t];
                    ushort4 v;
                    v.x = bf16c(a[0] + bb.x); v.y = bf16c(a[1] + bb.y);
                    v.z = bf16c(a[2] + bb.z); v.w = bf16c(a[3] + bb.w);
                    *(ushort4*)(Cp + rowb + nb) = v;
                }
            }
        }
    }
}

// K_bp: merged bngelu (2048 blocks) + proj GEMM (512 blocks, NT_W=4). grid 2560.
__global__ __launch_bounds__(256) void k_bp(
    const unsigned short* __restrict__ ydwb, const float* __restrict__ sc,
    const float* __restrict__ sh, unsigned short* __restrict__ x1f,
    const unsigned short* __restrict__ inpf, const unsigned short* __restrict__ wprojf,
    const float* __restrict__ bproj, unsigned short* __restrict__ xpad)
{
    int bid = blockIdx.x;
    if (bid < 2048) {
        bngelu_body(bid, threadIdx.x, ydwb, sc, sh, x1f);
    } else {
        int pbid = bid - 2048;
        fgemm_body<128, 8, 4, 3, 128>(pbid & 255, pbid >> 8, threadIdx.x,
            inpf, wprojf, bproj, (float*)xpad);
    }
}

// ---------------------------------------------------------------------------
// K6: FUSED offset/mask GEMM + DCNv3 core. block = 256 thr (4 waves),
// 32 positions (= 2 rowtiles). grid 1024.
// Phase 1: womb GEMM for these 32 rows -> bias-added bf16 offs/msk in LDS
//          (wave w: rowtile w&1, 7-tile chunk w>>1; bf16 rounding identical
//           to the old MODE-4 global store -> bit-identical numerics).
// Phase 2: per-(pos,g) softmax + bilinear gather from xpad (unchanged),
//          offsets/mask read from LDS. Output: fc1 hi-only A-frags.
// ---------------------------------------------------------------------------
__global__ __launch_bounds__(256) void k_dcn(
    const unsigned short* __restrict__ x1f, const unsigned short* __restrict__ womb,
    const float* __restrict__ boff, const float* __restrict__ bmask,
    const unsigned short* __restrict__ xpad, unsigned short* __restrict__ dcnf)
{
    __shared__ unsigned short offs_l[32][148];   // 9.25 KB (row 296 B, 8-div)
    __shared__ unsigned short msk_l[32][76];     // 4.75 KB (row 152 B, 8-div)
    int tid = threadIdx.x;
    int lane = tid & 63, wv = tid >> 6;          // 4 waves
    int rtl = wv & 1, chunk = wv >> 1;           // rowtile-local, 7-tile chunk
    int rt = blockIdx.x * 2 + rtl;

    // ---- phase 1: offs/msk GEMM into LDS ----
    {
        f32x4 acc[7];
        #pragma unroll
        for (int t = 0; t < 7; ++t) acc[t] = (f32x4){0.f, 0.f, 0.f, 0.f};
        const bf8_t* Ab = (const bf8_t*)x1f + (size_t)rt * 4 * 64 + lane;
        const bf8_t* WH = (const bf8_t*)womb + lane;
        #pragma unroll
        for (int kc = 0; kc < 4; ++kc) {
            bf8_t ah = Ab[kc * 64];
            #pragma unroll
            for (int t = 0; t < 7; ++t) {
                int tg = chunk * 7 + t;
                bf8_t wh = WH[(kc * 14 + tg) * 64];
                acc[t] = __builtin_amdgcn_mfma_f32_16x16x32_bf16(wh, ah, acc[t], 0, 0, 0);
            }
        }
        int m = rtl * 16 + (lane & 15);          // local row 0..31
        #pragma unroll
        for (int t = 0; t < 7; ++t) {
            int tg = chunk * 7 + t;
            int nb = tg * 16 + ((lane >> 4) << 2);
            f32x4 a = acc[t];
            if (nb < 144) {
                float4 bb = *(const float4*)(boff + nb);
                ushort4 v;
                v.x = bf16c(a[0] + bb.x); v.y = bf16c(a[1] + bb.y);
                v.z = bf16c(a[2] + bb.z); v.w = bf16c(a[3] + bb.w);
                *(ushort4*)(&offs_l[m][nb]) = v;
            } else {
                int col = nb - 144;
                if (col + 4 <= 72) {
                    float4 bb = *(const float4*)(bmask + col);
                    ushort4 v;
                    v.x = bf16c(a[0] + bb.x); v.y = bf16c(a[1] + bb.y);
                    v.z = bf16c(a[2] + bb.z); v.w = bf16c(a[3] + bb.w);
                    *(ushort4*)(&msk_l[m][col]) = v;
                }
            }
        }
    }
    __syncthreads();

    // ---- phase 2: softmax + bilinear gather ----
    int g = tid & 7;
    int lpos = tid >> 3;                         // 0..31
    int pos = blockIdx.x * 32 + lpos;
    int b = pos >> 12, hw = pos & 4095, h = hw >> 6, w = hw & 63;

    float e[9];
    float mx = -1e30f;
    #pragma unroll
    for (int p = 0; p < 9; ++p) { e[p] = bfd((unsigned)msk_l[lpos][g * 9 + p]); mx = fmaxf(mx, e[p]); }
    float ssum = 0.f;
    #pragma unroll
    for (int p = 0; p < 9; ++p) { e[p] = __expf(e[p] - mx); ssum += e[p]; }
    float inv = 1.0f / ssum;

    const unsigned short* xb = xpad + (size_t)b * 557568 + g * 16;  // 66*66*128/b

    float acc[16];
    #pragma unroll
    for (int i = 0; i < 16; ++i) acc[i] = 0.f;

    #pragma unroll
    for (int p = 0; p < 9; ++p) {
        unsigned dpair = *(const unsigned*)(&offs_l[lpos][g * 18 + p * 2]);
        float dx = bfd(dpair);
        float dy = __builtin_bit_cast(float, dpair & 0xFFFF0000u);
        float px = (float)(w + (p % 3)) + dx;   // padded-grid coords
        float py = (float)(h + (p / 3)) + dy;
        float x0f = floorf(px), y0f = floorf(py);
        float wx = px - x0f, wy = py - y0f;
        int ix = (int)x0f, iy = (int)y0f;
        int ix0 = max(min(ix, 65), 0),     ix1 = max(min(ix + 1, 65), 0);
        int iy0 = max(min(iy, 65), 0),     iy1 = max(min(iy + 1, 65), 0);
        int r0 = iy0 * 66, r1 = iy1 * 66;

        float mp  = e[p] * inv;
        float w11 = wy * wx * mp;
        float w10 = wy * mp - w11;
        float w01 = wx * mp - w11;
        float w00 = mp - w01 - w10 - w11;

        const unsigned short* c00 = xb + (size_t)(r0 + ix0) * 128;
        const unsigned short* c01 = xb + (size_t)(r0 + ix1) * 128;
        const unsigned short* c10 = xb + (size_t)(r1 + ix0) * 128;
        const unsigned short* c11 = xb + (size_t)(r1 + ix1) * 128;

        uint4 a00 = *(const uint4*)(c00), b00 = *(const uint4*)(c00 + 8);
        uint4 a01 = *(const uint4*)(c01), b01 = *(const uint4*)(c01 + 8);
        uint4 a10 = *(const uint4*)(c10), b10 = *(const uint4*)(c10 + 8);
        uint4 a11 = *(const uint4*)(c11), b11 = *(const uint4*)(c11 + 8);

        ufma(acc,     a00, w00); ufma(acc + 8, b00, w00);
        ufma(acc,     a01, w01); ufma(acc + 8, b01, w01);
        ufma(acc,     a10, w10); ufma(acc + 8, b10, w10);
        ufma(acc,     a11, w11); ufma(acc + 8, b11, w11);
    }

    // pack 16 channels as two hi-only frag groups
    int rto = pos >> 4, kc = g >> 1;
    int lp0 = (pos & 15) + (g & 1) * 32;
    size_t fb = ((size_t)rto * 4 + kc) * 512 + (size_t)lp0 * 8;
    uint4 hiA = pack8hi(acc);
    uint4 hiB = pack8hi(acc + 8);
    *(uint4*)(dcnf + fb)       = hiA;
    *(uint4*)(dcnf + fb + 128) = hiB;   // lp0+16
}

// ---------------------------------------------------------------------------
// K7: fused output MLP. block = 512 threads (8 waves) = 2 rowtile-PAIRS.
// ---------------------------------------------------------------------------
__global__ __launch_bounds__(512) void k_mlp(
    const unsigned short* __restrict__ dcnf, const unsigned short* __restrict__ wf1,
    const float* __restrict__ bfc1, const unsigned short* __restrict__ wf2,
    const float* __restrict__ bfc2, float* __restrict__ out)
{
    __shared__ unsigned short hid[4][16][264];   // 4 rowtiles, 33.8 KB
    int tid = threadIdx.x;
    int lane = tid & 63, w = tid >> 6;           // 8 waves
    int pr = w & 1, chunk = w >> 1;              // pair-local, chunk 0..3
    int bp = blockIdx.x * 2 + pr;                // pair id 0..1023
    int rt0 = bp * 2;                            // rowtiles rt0, rt0+1
    int m = lane & 15, hi4 = (lane >> 4) << 2;

    // ---- fc1: hidden tiles chunk*4 .. +3, rowtiles rt0, rt0+1 ----
    f32x4 acc[2][4];
    #pragma unroll
    for (int r = 0; r < 2; ++r)
        #pragma unroll
        for (int t = 0; t < 4; ++t) acc[r][t] = (f32x4){0.f, 0.f, 0.f, 0.f};
    const bf8_t* Ab0 = (const bf8_t*)dcnf + (size_t)rt0 * 4 * 64 + lane;  // KC=4 hi-only
    const bf8_t* Ab1 = Ab0 + 4 * 64;
    const bf8_t* WH1 = (const bf8_t*)wf1 + lane;
    #pragma unroll
    for (int kc = 0; kc < 4; ++kc) {
        bf8_t a0 = Ab0[kc * 64];
        bf8_t a1 = Ab1[kc * 64];
        #pragma unroll
        for (int t = 0; t < 4; ++t) {
            int tg = chunk * 4 + t;
            bf8_t wh = WH1[(kc * 16 + tg) * 64];
            acc[0][t] = __builtin_amdgcn_mfma_f32_16x16x32_bf16(wh, a0, acc[0][t], 0, 0, 0);
            acc[1][t] = __builtin_amdgcn_mfma_f32_16x16x32_bf16(wh, a1, acc[1][t], 0, 0, 0);
        }
    }
    // GELU + bf16 -> LDS
    #pragma unroll
    for (int r = 0; r < 2; ++r) {
        #pragma unroll
        for (int t = 0; t < 4; ++t) {
            int nb = (chunk * 4 + t) * 16 + hi4;
            float4 bb = *(const float4*)(bfc1 + nb);
            ushort4 v;
            v.x = bf16c(gelu_exact(acc[r][t][0] + bb.x));
            v.y = bf16c(gelu_exact(acc[r][t][1] + bb.y));
            v.z = bf16c(gelu_exact(acc[r][t][2] + bb.z));
            v.w = bf16c(gelu_exact(acc[r][t][3] + bb.w));
            *(ushort4*)(&hid[pr * 2 + r][m][nb]) = v;
        }
    }

    __syncthreads();

    // ---- fc2: out tiles chunk*2 .. +1, rowtiles rt0, rt0+1 ----
    f32x4 acc2[2][2];
    #pragma unroll
    for (int r = 0; r < 2; ++r)
        #pragma unroll
        for (int t = 0; t < 2; ++t) acc2[r][t] = (f32x4){0.f, 0.f, 0.f, 0.f};
    const bf8_t* WH2 = (const bf8_t*)wf2 + lane;
    #pragma unroll
    for (int kc = 0; kc < 8; ++kc) {
        bf8_t ah0 = *(const bf8_t*)(&hid[pr * 2 + 0][m][kc * 32 + (lane >> 4) * 8]);
        bf8_t ah1 = *(const bf8_t*)(&hid[pr * 2 + 1][m][kc * 32 + (lane >> 4) * 8]);
        #pragma unroll
        for (int t = 0; t < 2; ++t) {
            int tg = chunk * 2 + t;
            bf8_t wh = WH2[(kc * 8 + tg) * 64];
            acc2[0][t] = __builtin_amdgcn_mfma_f32_16x16x32_bf16(ah0, wh, acc2[0][t], 0, 0, 0);
            acc2[1][t] = __builtin_amdgcn_mfma_f32_16x16x32_bf16(ah1, wh, acc2[1][t], 0, 0, 0);
        }
    }
    // NCHW transposed fp32 store
    #pragma unroll
    for (int r = 0; r < 2; ++r) {
        int m4 = (rt0 + r) * 16 + hi4;
        int b = m4 >> 12, hw = m4 & 4095;
        #pragma unroll
        for (int t = 0; t < 2; ++t) {
            int n = (chunk * 2 + t) * 16 + m;
            float bb = bfc2[n];
            f32x4 a = acc2[r][t];
            float4 v = {a[0] + bb, a[1] + bb, a[2] + bb, a[3] + bb};
            *(float4*)(out + (((size_t)(b * 128 + n)) << 12) + hw) = v;
        }
    }
}

// ---------------------------------------------------------------------------
extern "C" void kernel_launch(void* const* d_in, const int* in_sizes, int n_in,
                              void* d_out, int out_size, void* d_ws, size_t ws_size,
                              hipStream_t stream)
{
    const float* inp   = (const float*)d_in[0];
    const float* wproj = (const float*)d_in[1];
    const float* bproj = (const float*)d_in[2];
    const float* dww   = (const float*)d_in[3];
    const float* dwb   = (const float*)d_in[4];
    const float* gamma = (const float*)d_in[5];
    const float* beta  = (const float*)d_in[6];
    const float* woff  = (const float*)d_in[7];
    const float* boff  = (const float*)d_in[8];
    const float* wmask = (const float*)d_in[9];
    const float* bmask = (const float*)d_in[10];
    const float* wfc1  = (const float*)d_in[11];
    const float* bfc1  = (const float*)d_in[12];
    const float* wfc2  = (const float*)d_in[13];
    const float* bfc2  = (const float*)d_in[14];
    float* out = (float*)d_out;
    float* ws  = (float*)d_ws;

    // xpad (bf16)
    unsigned short* xpad = (unsigned short*)ws;              // 4,460,544 ush [bp..dcn]
    // Region A at ws+9179136: inpf [pd..bp-proj], dcnf [dcn..mlp]
    unsigned short* inpf  = (unsigned short*)(ws + 9179136);   // 4,194,304 ush hi-only
    unsigned short* dcnf  = (unsigned short*)(ws + 9179136);   // 4,194,304 ush hi-only
    unsigned short* x1f   = (unsigned short*)(ws + 13373440);  // 4,194,304 ush hi-only [bp..dcn]
    unsigned short* ydwb  = (unsigned short*)(ws + 15470592);  // 4,194,304 ush bf16 [pd..bp]
    // Rest
    float* psum = ws + 19927040;                         // 65,536 f
    float* psq  = ws + 19992576;                         // 65,536 f
    float* scs  = ws + 20058112;                         // 128 f
    float* shs  = ws + 20058240;                         // 128 f
    unsigned short* wfr = (unsigned short*)(ws + 20058368);  // 176,128 ush

    unsigned short* wproj_f = wfr;            // hi-only, 16384
    unsigned short* womb_f  = wfr + 16384;    // hi-only combined, 28672
    unsigned short* wfc1_f  = wfr + 45056;    // hi(/lo stored), hi consumed
    unsigned short* wfc2_f  = wfr + 110592;   // hi(/lo stored), hi consumed

    k_pd<<<696, 256, 0, stream>>>(inp, inpf, xpad, wproj, woff, wmask, wfc1, wfc2,
                                  wfr, dww, dwb, ydwb, psum, psq);
    k_bnstats<<<128, 256, 0, stream>>>(psum, psq, gamma, beta, scs, shs);
    k_bp<<<2560, 256, 0, stream>>>(ydwb, scs, shs, x1f, inpf, wproj_f, bproj, xpad);
    k_dcn<<<1024, 256, 0, stream>>>(x1f, womb_f, boff, bmask, xpad, dcnf);
    k_mlp<<<512, 512, 0, stream>>>(dcnf, wfc1_f, bfc1, wfc2_f, bfc2, out);
}

// Round 16
// 82.677 us; speedup vs baseline: 1.3822x; 1.0395x over previous
//
#include <hip/hip_runtime.h>
#include <math.h>

#define NPOS  32768      // B*H*W
#define CDIM  128
#define HS    64
#define WSZ   64

typedef __bf16 bf8_t  __attribute__((ext_vector_type(8)));
typedef float  f32x4  __attribute__((ext_vector_type(4)));

__device__ __forceinline__ float gelu_exact(float x) {
    return 0.5f * x * (1.0f + erff(x * 0.70710678118654752f));
}

__device__ __forceinline__ unsigned short bf16c(float v) {
    return __builtin_bit_cast(unsigned short, (__bf16)v);
}

__device__ __forceinline__ uint4 pack8hi(const float* v) {
    unsigned hh[8];
    #pragma unroll
    for (int i = 0; i < 8; ++i) hh[i] = (unsigned)bf16c(v[i]);
    return make_uint4(hh[0] | (hh[1] << 16), hh[2] | (hh[3] << 16),
                      hh[4] | (hh[5] << 16), hh[6] | (hh[7] << 16));
}

__device__ __forceinline__ float bfd(unsigned u) {        // low 16 bits as bf16
    return __builtin_bit_cast(float, u << 16);
}

// unpack uint4 (8 bf16) and fma into acc[8] with weight
__device__ __forceinline__ void ufma(float* acc, uint4 c, float wgt) {
    const unsigned* cc = (const unsigned*)&c;
    #pragma unroll
    for (int j = 0; j < 4; ++j) {
        acc[2 * j]     += __builtin_bit_cast(float, cc[j] << 16) * wgt;
        acc[2 * j + 1] += __builtin_bit_cast(float, cc[j] & 0xFFFF0000u) * wgt;
    }
}

// ---------------------------------------------------------------------------
// A-frag layouts (K=KC*32): hi-only buffers: block(rt,kc) = 512 ush
//  elem: lane*8 + i, lane = (row%16) + ((k%32)/8)*16, i = k%8
// ---------------------------------------------------------------------------

// ---------------------------------------------------------------------------
// prep body: blocks [0,130) border: zero 1-px ring of bf16 xpad
//            [130,184) wprep: weights -> frag bf16
// ---------------------------------------------------------------------------
__device__ void prep_body(
    int bid, int tid,
    unsigned short* __restrict__ xpad,
    const float* __restrict__ w0, const float* __restrict__ w1,
    const float* __restrict__ w2, const float* __restrict__ w3,
    const float* __restrict__ w4, unsigned short* __restrict__ wb)
{
    if (bid < 130) {
        int idx = bid * 256 + tid;         // 2080 cells * 16
        if (idx < 33280) {
            int c8 = (idx & 15) * 8;
            int cell = idx >> 4;
            int b = cell / 260, r = cell % 260;
            int h, w;
            if (r < 66)       { h = 0;  w = r; }
            else if (r < 132) { h = 65; w = r - 66; }
            else { int rr = r - 132; h = 1 + (rr >> 1); w = (rr & 1) * 65; }
            size_t o = (((size_t)b * 66 + h) * 66 + w) * 128 + c8;
            *(uint4*)(xpad + o) = make_uint4(0u, 0u, 0u, 0u);
        }
    } else {
        int sub = (bid - 130) * 4 + (tid >> 6);    // 0..215
        int lane = tid & 63;
        int NT, K, local; unsigned short* out; bool hl; bool comb = false;
        const float* W = nullptr; int N = 0;
        if (sub < 32)       { NT = 8;  K = 128; out = wb;          local = sub;       hl = false; W = w0; N = 128; }
        else if (sub < 88)  { NT = 14; K = 128; out = wb + 16384;  local = sub - 32;  hl = false; comb = true; }
        else if (sub < 152) { NT = 16; K = 128; out = wb + 45056;  local = sub - 88;  hl = true;  W = w3; N = 256; }
        else                { NT = 8;  K = 256; out = wb + 110592; local = sub - 152; hl = true;  W = w4; N = 128; }
        int KC = K / 32;
        int unit = KC * NT * 512;
        int kc = local / NT, t = local % NT;
        int nt = t * 16 + (lane & 15);
        const float* Wp = W; int n = nt, Nv = N;
        if (comb) {
            if (t < 9) { Wp = w1; n = nt;       Nv = 144; }
            else       { Wp = w2; n = nt - 144; Nv = 72;  }
        }
        int kb = kc * 32 + (lane >> 4) * 8;
        size_t base = ((size_t)local * 64 + lane) * 8;
        #pragma unroll
        for (int i = 0; i < 8; ++i) {
            float v = (n < Nv) ? Wp[(size_t)n * K + kb + i] : 0.f;
            __bf16 h = (__bf16)v;
            out[base + i] = __builtin_bit_cast(unsigned short, h);
            if (hl) {
                __bf16 l = (__bf16)(v - (float)h);
                out[unit + base + i] = __builtin_bit_cast(unsigned short, l);
            }
        }
    }
}

// ---------------------------------------------------------------------------
// dwconv body: depthwise 3x3 (NHWC) -> bf16 ydw + partial BN sums (fp32)
//              + center-tap -> inpf hi-only frags (folded aprep)
// ---------------------------------------------------------------------------
__device__ void dwconv_body(
    int blk, int tid,
    const float* __restrict__ inp, const float* __restrict__ dww,
    const float* __restrict__ dwb, unsigned short* __restrict__ ydwb,
    float* __restrict__ psum, float* __restrict__ psq,
    unsigned short* __restrict__ inpf)
{
    int b = blk >> 6, h = blk & 63;
    int c4 = (tid & 31) * 4;
    int wg = tid >> 5;               // 0..7

    float wreg[4][9];
    #pragma unroll
    for (int cc = 0; cc < 4; ++cc)
        #pragma unroll
        for (int p = 0; p < 9; ++p)
            wreg[cc][p] = dww[(c4 + cc) * 9 + p];
    float bia[4];
    #pragma unroll
    for (int cc = 0; cc < 4; ++cc) bia[cc] = dwb[c4 + cc];

    float s4[4] = {0,0,0,0}, q4[4] = {0,0,0,0};
    const float* ibase = inp + (size_t)(b << 12) * CDIM;

    for (int i = 0; i < 8; ++i) {
        int w = wg + i * 8;
        float acc[4] = {bia[0], bia[1], bia[2], bia[3]};
        float4 ctr;
        #pragma unroll
        for (int ky = 0; ky < 3; ++ky) {
            int yy = h + ky - 1;
            if (yy < 0 || yy >= HS) continue;
            #pragma unroll
            for (int kx = 0; kx < 3; ++kx) {
                int xx = w + kx - 1;
                if (xx < 0 || xx >= WSZ) continue;
                float4 v = *(const float4*)(ibase + (size_t)(yy * 64 + xx) * CDIM + c4);
                if (ky == 1 && kx == 1) ctr = v;
                int p = ky * 3 + kx;
                acc[0] += v.x * wreg[0][p];
                acc[1] += v.y * wreg[1][p];
                acc[2] += v.z * wreg[2][p];
                acc[3] += v.w * wreg[3][p];
            }
        }
        int r = (b << 12) + h * 64 + w;
        ushort4 o;
        o.x = bf16c(acc[0]); o.y = bf16c(acc[1]);
        o.z = bf16c(acc[2]); o.w = bf16c(acc[3]);
        *(ushort4*)(ydwb + (size_t)r * CDIM + c4) = o;
        // folded aprep: center tap -> inpf hi-only frag (4 channels)
        {
            int rt = r >> 4, kc = c4 >> 5;
            int lp = (r & 15) + ((c4 & 31) >> 3) * 16;
            int i0 = c4 & 7;
            unsigned u0 = (unsigned)bf16c(ctr.x) | ((unsigned)bf16c(ctr.y) << 16);
            unsigned u1 = (unsigned)bf16c(ctr.z) | ((unsigned)bf16c(ctr.w) << 16);
            *(uint2*)(inpf + ((size_t)rt * 4 + kc) * 512 + lp * 8 + i0) = make_uint2(u0, u1);
        }
        #pragma unroll
        for (int cc = 0; cc < 4; ++cc) { s4[cc] += acc[cc]; q4[cc] += acc[cc] * acc[cc]; }
    }

    __shared__ float ls[8][128], lq[8][128];
    #pragma unroll
    for (int cc = 0; cc < 4; ++cc) { ls[wg][c4 + cc] = s4[cc]; lq[wg][c4 + cc] = q4[cc]; }
    __syncthreads();
    if (tid < 128) {
        float s = 0.f, q = 0.f;
        #pragma unroll
        for (int r = 0; r < 8; ++r) { s += ls[r][tid]; q += lq[r][tid]; }
        psum[blk * 128 + tid] = s;
        psq [blk * 128 + tid] = q;
    }
}

// K_pd: merged prep (184 blocks) + dwconv (512 blocks). grid 696.
__global__ __launch_bounds__(256) void k_pd(
    const float* __restrict__ inp, unsigned short* __restrict__ inpf,
    unsigned short* __restrict__ xpad,
    const float* __restrict__ w0, const float* __restrict__ w1,
    const float* __restrict__ w2, const float* __restrict__ w3,
    const float* __restrict__ w4, unsigned short* __restrict__ wb,
    const float* __restrict__ dww, const float* __restrict__ dwb,
    unsigned short* __restrict__ ydwb, float* __restrict__ psum,
    float* __restrict__ psq)
{
    int bid = blockIdx.x;
    if (bid < 184) prep_body(bid, threadIdx.x, xpad, w0, w1, w2, w3, w4, wb);
    else           dwconv_body(bid - 184, threadIdx.x, inp, dww, dwb, ydwb, psum, psq, inpf);
}

// ---------------------------------------------------------------------------
// K2: finalize BN stats -> scale/shift per channel.
// ---------------------------------------------------------------------------
__global__ __launch_bounds__(256) void k_bnstats(
    const float* __restrict__ psum, const float* __restrict__ psq,
    const float* __restrict__ gamma, const float* __restrict__ beta,
    float* __restrict__ sc, float* __restrict__ sh)
{
    int c = blockIdx.x;
    int t = threadIdx.x;
    float s = psum[t * 128 + c] + psum[(t + 256) * 128 + c];
    float q = psq [t * 128 + c] + psq [(t + 256) * 128 + c];
    __shared__ float rs[256], rq[256];
    rs[t] = s; rq[t] = q; __syncthreads();
    for (int off = 128; off > 0; off >>= 1) {
        if (t < off) { rs[t] += rs[t + off]; rq[t] += rq[t + off]; }
        __syncthreads();
    }
    if (t == 0) {
        float mean = rs[0] * (1.0f / 32768.0f);
        float var  = rq[0] * (1.0f / 32768.0f) - mean * mean;
        float scale = gamma[c] * rsqrtf(var + 1e-5f);
        sc[c] = scale;
        sh[c] = beta[c] - mean * scale;
    }
}

// ---------------------------------------------------------------------------
// bngelu body: bf16 ydw -> BN + exact GELU -> x1 hi-only frags.
// ---------------------------------------------------------------------------
__device__ void bngelu_body(
    int bid, int tid,
    const unsigned short* __restrict__ ydwb, const float* __restrict__ sc,
    const float* __restrict__ sh, unsigned short* __restrict__ dst)
{
    int idx = bid * 256 + tid;   // 32768*16
    int r = idx >> 4, k8 = (idx & 15) * 8;
    uint4 yv = *(const uint4*)(ydwb + (size_t)r * 128 + k8);
    const unsigned* cc = (const unsigned*)&yv;
    float t[8];
    #pragma unroll
    for (int j = 0; j < 4; ++j) {
        t[2 * j]     = bfd(cc[j]);
        t[2 * j + 1] = __builtin_bit_cast(float, cc[j] & 0xFFFF0000u);
    }
    float s[8], h[8];
    *(float4*)(s)     = *(const float4*)(sc + k8);
    *(float4*)(s + 4) = *(const float4*)(sc + k8 + 4);
    *(float4*)(h)     = *(const float4*)(sh + k8);
    *(float4*)(h + 4) = *(const float4*)(sh + k8 + 4);
    #pragma unroll
    for (int i = 0; i < 8; ++i) t[i] = gelu_exact(t[i] * s[i] + h[i]);
    uint4 hi = pack8hi(t);
    int rt = r >> 4, kc = k8 >> 5, lp = (r & 15) + ((k8 & 31) >> 3) * 16;
    size_t base = ((size_t)rt * 4 + kc) * 512 + lp * 8;
    *(uint4*)(dst + base) = hi;
}

// ---------------------------------------------------------------------------
// Frag-stream MFMA GEMM body (hi-only). MODE 3: bf16 padded store.
// ---------------------------------------------------------------------------
template<int KDIM, int NT_TOT, int NT_W, int MODE, int NV>
__device__ void fgemm_body(
    int bx, int by, int tid,
    const unsigned short* __restrict__ AF, const unsigned short* __restrict__ WF,
    const float* __restrict__ bias, float* __restrict__ C)
{
    constexpr int KC = KDIM / 32;
    int lane = tid & 63, w = tid >> 6;
    int rt0 = bx * 8 + w * 2;      // 2 rowtiles per wave
    int t0 = by * NT_W;            // n-tile chunk base

    f32x4 acc[2][NT_W];
    #pragma unroll
    for (int rt = 0; rt < 2; ++rt)
        #pragma unroll
        for (int t = 0; t < NT_W; ++t) acc[rt][t] = (f32x4){0.f, 0.f, 0.f, 0.f};

    const bf8_t* Ab0 = (const bf8_t*)AF + (size_t)rt0 * KC * 64 + lane;
    const bf8_t* Ab1 = Ab0 + KC * 64;
    const bf8_t* WHp = (const bf8_t*)WF + lane;

    #pragma unroll
    for (int kc = 0; kc < KC; ++kc) {
        bf8_t a0h = Ab0[kc * 64];
        bf8_t a1h = Ab1[kc * 64];
        #pragma unroll
        for (int t = 0; t < NT_W; ++t) {
            int tg = t0 + t;
            if (tg < NT_TOT) {
                bf8_t wh = WHp[(kc * NT_TOT + tg) * 64];
                acc[0][t] = __builtin_amdgcn_mfma_f32_16x16x32_bf16(wh, a0h, acc[0][t], 0, 0, 0);
                acc[1][t] = __builtin_amdgcn_mfma_f32_16x16x32_bf16(wh, a1h, acc[1][t], 0, 0, 0);
            }
        }
    }

    #pragma unroll
    for (int rt = 0; rt < 2; ++rt) {
        if (MODE == 3) {
            unsigned short* Cp = (unsigned short*)C;
            int m = (rt0 + rt) * 16 + (lane & 15);
            int bb_ = m >> 12, hwm = m & 4095;
            size_t rowb = (((size_t)bb_ * 66 + (hwm >> 6) + 1) * 66 + (hwm & 63) + 1) * 128;
            #pragma unroll
            for (int t = 0; t < NT_W; ++t) {
                int tg = t0 + t;
                int nb = tg * 16 + ((lane >> 4) << 2);
                if (tg < NT_TOT) {
                    float4 bb = *(const float4*)(bias + nb);
                    f32x4 a = acc[rt][t];
                    ushort4 v;
                    v.x = bf16c(a[0] + bb.x); v.y = bf16c(a[1] + bb.y);
                    v.z = bf16c(a[2] + bb.z); v.w = bf16c(a[3] + bb.w);
                    *(ushort4*)(Cp + rowb + nb) = v;
                }
            }
        }
    }
}

// K_bp: merged bngelu (2048 blocks) + proj GEMM (512 blocks, NT_W=4). grid 2560.
__global__ __launch_bounds__(256) void k_bp(
    const unsigned short* __restrict__ ydwb, const float* __restrict__ sc,
    const float* __restrict__ sh, unsigned short* __restrict__ x1f,
    const unsigned short* __restrict__ inpf, const unsigned short* __restrict__ wprojf,
    const float* __restrict__ bproj, unsigned short* __restrict__ xpad)
{
    int bid = blockIdx.x;
    if (bid < 2048) {
        bngelu_body(bid, threadIdx.x, ydwb, sc, sh, x1f);
    } else {
        int pbid = bid - 2048;
        fgemm_body<128, 8, 4, 3, 128>(pbid & 255, pbid >> 8, threadIdx.x,
            inpf, wprojf, bproj, (float*)xpad);
    }
}

// ---------------------------------------------------------------------------
// K6: FUSED offset/mask GEMM + DCNv3 core, v2 (occupancy-restored).
// block = 512 threads (8 waves), 32 positions (= 2 rowtiles). grid 1024.
// Phase 1: 8 waves, wave w: rowtile w&1, 4-tile chunk w>>1 (tg<14 guard).
//          acc[4] only -> low VGPR. bf16 offs/msk -> LDS (bit-identical
//          rounding to old global store).
// Phase 2: thread = (pos, g, half): 8 channels each, acc[8] + 4 uint4 in
//          flight. Softmax duplicated x2 (VALU idle). 8192 waves total.
// ---------------------------------------------------------------------------
__global__ __launch_bounds__(512) void k_dcn(
    const unsigned short* __restrict__ x1f, const unsigned short* __restrict__ womb,
    const float* __restrict__ boff, const float* __restrict__ bmask,
    const unsigned short* __restrict__ xpad, unsigned short* __restrict__ dcnf)
{
    __shared__ unsigned short offs_l[32][148];   // 9.25 KB
    __shared__ unsigned short msk_l[32][76];     // 4.75 KB
    int tid = threadIdx.x;
    int lane = tid & 63, wv = tid >> 6;          // 8 waves
    int rtl = wv & 1, chunk = wv >> 1;           // rowtile-local, 4-tile chunk
    int rt = blockIdx.x * 2 + rtl;

    // ---- phase 1: offs/msk GEMM into LDS ----
    {
        f32x4 acc[4];
        #pragma unroll
        for (int t = 0; t < 4; ++t) acc[t] = (f32x4){0.f, 0.f, 0.f, 0.f};
        const bf8_t* Ab = (const bf8_t*)x1f + (size_t)rt * 4 * 64 + lane;
        const bf8_t* WH = (const bf8_t*)womb + lane;
        #pragma unroll
        for (int kc = 0; kc < 4; ++kc) {
            bf8_t ah = Ab[kc * 64];
            #pragma unroll
            for (int t = 0; t < 4; ++t) {
                int tg = chunk * 4 + t;
                if (tg < 14) {
                    bf8_t wh = WH[(kc * 14 + tg) * 64];
                    acc[t] = __builtin_amdgcn_mfma_f32_16x16x32_bf16(wh, ah, acc[t], 0, 0, 0);
                }
            }
        }
        int m = rtl * 16 + (lane & 15);          // local row 0..31
        #pragma unroll
        for (int t = 0; t < 4; ++t) {
            int tg = chunk * 4 + t;
            if (tg < 14) {
                int nb = tg * 16 + ((lane >> 4) << 2);
                f32x4 a = acc[t];
                if (nb < 144) {
                    float4 bb = *(const float4*)(boff + nb);
                    ushort4 v;
                    v.x = bf16c(a[0] + bb.x); v.y = bf16c(a[1] + bb.y);
                    v.z = bf16c(a[2] + bb.z); v.w = bf16c(a[3] + bb.w);
                    *(ushort4*)(&offs_l[m][nb]) = v;
                } else {
                    int col = nb - 144;
                    if (col + 4 <= 72) {
                        float4 bb = *(const float4*)(bmask + col);
                        ushort4 v;
                        v.x = bf16c(a[0] + bb.x); v.y = bf16c(a[1] + bb.y);
                        v.z = bf16c(a[2] + bb.z); v.w = bf16c(a[3] + bb.w);
                        *(ushort4*)(&msk_l[m][col]) = v;
                    }
                }
            }
        }
    }
    __syncthreads();

    // ---- phase 2: softmax + bilinear gather; thread = (pos, g, half) ----
    int q = tid & 1;
    int g = (tid >> 1) & 7;
    int lpos = tid >> 4;                         // 0..31
    int pos = blockIdx.x * 32 + lpos;
    int b = pos >> 12, hw = pos & 4095, h = hw >> 6, w = hw & 63;

    float e[9];
    float mx = -1e30f;
    #pragma unroll
    for (int p = 0; p < 9; ++p) { e[p] = bfd((unsigned)msk_l[lpos][g * 9 + p]); mx = fmaxf(mx, e[p]); }
    float ssum = 0.f;
    #pragma unroll
    for (int p = 0; p < 9; ++p) { e[p] = __expf(e[p] - mx); ssum += e[p]; }
    float inv = 1.0f / ssum;

    int ch = g * 16 + q * 8;
    const unsigned short* xb = xpad + (size_t)b * 557568 + ch;  // 66*66*128/b

    float acc[8];
    #pragma unroll
    for (int i = 0; i < 8; ++i) acc[i] = 0.f;

    #pragma unroll
    for (int p = 0; p < 9; ++p) {
        unsigned dpair = *(const unsigned*)(&offs_l[lpos][g * 18 + p * 2]);
        float dx = bfd(dpair);
        float dy = __builtin_bit_cast(float, dpair & 0xFFFF0000u);
        float px = (float)(w + (p % 3)) + dx;   // padded-grid coords
        float py = (float)(h + (p / 3)) + dy;
        float x0f = floorf(px), y0f = floorf(py);
        float wx = px - x0f, wy = py - y0f;
        int ix = (int)x0f, iy = (int)y0f;
        int ix0 = max(min(ix, 65), 0),     ix1 = max(min(ix + 1, 65), 0);
        int iy0 = max(min(iy, 65), 0),     iy1 = max(min(iy + 1, 65), 0);
        int r0 = iy0 * 66, r1 = iy1 * 66;

        float mp  = e[p] * inv;
        float w11 = wy * wx * mp;
        float w10 = wy * mp - w11;
        float w01 = wx * mp - w11;
        float w00 = mp - w01 - w10 - w11;

        uint4 s00 = *(const uint4*)(xb + (size_t)(r0 + ix0) * 128);
        uint4 s01 = *(const uint4*)(xb + (size_t)(r0 + ix1) * 128);
        uint4 s10 = *(const uint4*)(xb + (size_t)(r1 + ix0) * 128);
        uint4 s11 = *(const uint4*)(xb + (size_t)(r1 + ix1) * 128);

        ufma(acc, s00, w00);
        ufma(acc, s01, w01);
        ufma(acc, s10, w10);
        ufma(acc, s11, w11);
    }

    // pack 8 channels as one hi-only frag group
    int rto = pos >> 4, kc = ch >> 5;                       // kc = g>>1
    int lp = (pos & 15) + (((g & 1) << 1) + q) * 16;        // ((ch&31)>>3)*16
    size_t fb = ((size_t)rto * 4 + kc) * 512 + (size_t)lp * 8;
    *(uint4*)(dcnf + fb) = pack8hi(acc);
}

// ---------------------------------------------------------------------------
// K7: fused output MLP. block = 512 threads (8 waves) = 2 rowtile-PAIRS.
// ---------------------------------------------------------------------------
__global__ __launch_bounds__(512) void k_mlp(
    const unsigned short* __restrict__ dcnf, const unsigned short* __restrict__ wf1,
    const float* __restrict__ bfc1, const unsigned short* __restrict__ wf2,
    const float* __restrict__ bfc2, float* __restrict__ out)
{
    __shared__ unsigned short hid[4][16][264];   // 4 rowtiles, 33.8 KB
    int tid = threadIdx.x;
    int lane = tid & 63, w = tid >> 6;           // 8 waves
    int pr = w & 1, chunk = w >> 1;              // pair-local, chunk 0..3
    int bp = blockIdx.x * 2 + pr;                // pair id 0..1023
    int rt0 = bp * 2;                            // rowtiles rt0, rt0+1
    int m = lane & 15, hi4 = (lane >> 4) << 2;

    // ---- fc1: hidden tiles chunk*4 .. +3, rowtiles rt0, rt0+1 ----
    f32x4 acc[2][4];
    #pragma unroll
    for (int r = 0; r < 2; ++r)
        #pragma unroll
        for (int t = 0; t < 4; ++t) acc[r][t] = (f32x4){0.f, 0.f, 0.f, 0.f};
    const bf8_t* Ab0 = (const bf8_t*)dcnf + (size_t)rt0 * 4 * 64 + lane;  // KC=4 hi-only
    const bf8_t* Ab1 = Ab0 + 4 * 64;
    const bf8_t* WH1 = (const bf8_t*)wf1 + lane;
    #pragma unroll
    for (int kc = 0; kc < 4; ++kc) {
        bf8_t a0 = Ab0[kc * 64];
        bf8_t a1 = Ab1[kc * 64];
        #pragma unroll
        for (int t = 0; t < 4; ++t) {
            int tg = chunk * 4 + t;
            bf8_t wh = WH1[(kc * 16 + tg) * 64];
            acc[0][t] = __builtin_amdgcn_mfma_f32_16x16x32_bf16(wh, a0, acc[0][t], 0, 0, 0);
            acc[1][t] = __builtin_amdgcn_mfma_f32_16x16x32_bf16(wh, a1, acc[1][t], 0, 0, 0);
        }
    }
    // GELU + bf16 -> LDS
    #pragma unroll
    for (int r = 0; r < 2; ++r) {
        #pragma unroll
        for (int t = 0; t < 4; ++t) {
            int nb = (chunk * 4 + t) * 16 + hi4;
            float4 bb = *(const float4*)(bfc1 + nb);
            ushort4 v;
            v.x = bf16c(gelu_exact(acc[r][t][0] + bb.x));
            v.y = bf16c(gelu_exact(acc[r][t][1] + bb.y));
            v.z = bf16c(gelu_exact(acc[r][t][2] + bb.z));
            v.w = bf16c(gelu_exact(acc[r][t][3] + bb.w));
            *(ushort4*)(&hid[pr * 2 + r][m][nb]) = v;
        }
    }

    __syncthreads();

    // ---- fc2: out tiles chunk*2 .. +1, rowtiles rt0, rt0+1 ----
    f32x4 acc2[2][2];
    #pragma unroll
    for (int r = 0; r < 2; ++r)
        #pragma unroll
        for (int t = 0; t < 2; ++t) acc2[r][t] = (f32x4){0.f, 0.f, 0.f, 0.f};
    const bf8_t* WH2 = (const bf8_t*)wf2 + lane;
    #pragma unroll
    for (int kc = 0; kc < 8; ++kc) {
        bf8_t ah0 = *(const bf8_t*)(&hid[pr * 2 + 0][m][kc * 32 + (lane >> 4) * 8]);
        bf8_t ah1 = *(const bf8_t*)(&hid[pr * 2 + 1][m][kc * 32 + (lane >> 4) * 8]);
        #pragma unroll
        for (int t = 0; t < 2; ++t) {
            int tg = chunk * 2 + t;
            bf8_t wh = WH2[(kc * 8 + tg) * 64];
            acc2[0][t] = __builtin_amdgcn_mfma_f32_16x16x32_bf16(ah0, wh, acc2[0][t], 0, 0, 0);
            acc2[1][t] = __builtin_amdgcn_mfma_f32_16x16x32_bf16(ah1, wh, acc2[1][t], 0, 0, 0);
        }
    }
    // NCHW transposed fp32 store
    #pragma unroll
    for (int r = 0; r < 2; ++r) {
        int m4 = (rt0 + r) * 16 + hi4;
        int b = m4 >> 12, hw = m4 & 4095;
        #pragma unroll
        for (int t = 0; t < 2; ++t) {
            int n = (chunk * 2 + t) * 16 + m;
            float bb = bfc2[n];
            f32x4 a = acc2[r][t];
            float4 v = {a[0] + bb, a[1] + bb, a[2] + bb, a[3] + bb};
            *(float4*)(out + (((size_t)(b * 128 + n)) << 12) + hw) = v;
        }
    }
}

// ---------------------------------------------------------------------------
extern "C" void kernel_launch(void* const* d_in, const int* in_sizes, int n_in,
                              void* d_out, int out_size, void* d_ws, size_t ws_size,
                              hipStream_t stream)
{
    const float* inp   = (const float*)d_in[0];
    const float* wproj = (const float*)d_in[1];
    const float* bproj = (const float*)d_in[2];
    const float* dww   = (const float*)d_in[3];
    const float* dwb   = (const float*)d_in[4];
    const float* gamma = (const float*)d_in[5];
    const float* beta  = (const float*)d_in[6];
    const float* woff  = (const float*)d_in[7];
    const float* boff  = (const float*)d_in[8];
    const float* wmask = (const float*)d_in[9];
    const float* bmask = (const float*)d_in[10];
    const float* wfc1  = (const float*)d_in[11];
    const float* bfc1  = (const float*)d_in[12];
    const float* wfc2  = (const float*)d_in[13];
    const float* bfc2  = (const float*)d_in[14];
    float* out = (float*)d_out;
    float* ws  = (float*)d_ws;

    // xpad (bf16)
    unsigned short* xpad = (unsigned short*)ws;              // 4,460,544 ush [bp..dcn]
    // Region A at ws+9179136: inpf [pd..bp-proj], dcnf [dcn..mlp]
    unsigned short* inpf  = (unsigned short*)(ws + 9179136);   // 4,194,304 ush hi-only
    unsigned short* dcnf  = (unsigned short*)(ws + 9179136);   // 4,194,304 ush hi-only
    unsigned short* x1f   = (unsigned short*)(ws + 13373440);  // 4,194,304 ush hi-only [bp..dcn]
    unsigned short* ydwb  = (unsigned short*)(ws + 15470592);  // 4,194,304 ush bf16 [pd..bp]
    // Rest
    float* psum = ws + 19927040;                         // 65,536 f
    float* psq  = ws + 19992576;                         // 65,536 f
    float* scs  = ws + 20058112;                         // 128 f
    float* shs  = ws + 20058240;                         // 128 f
    unsigned short* wfr = (unsigned short*)(ws + 20058368);  // 176,128 ush

    unsigned short* wproj_f = wfr;            // hi-only, 16384
    unsigned short* womb_f  = wfr + 16384;    // hi-only combined, 28672
    unsigned short* wfc1_f  = wfr + 45056;    // hi(/lo stored), hi consumed
    unsigned short* wfc2_f  = wfr + 110592;   // hi(/lo stored), hi consumed

    k_pd<<<696, 256, 0, stream>>>(inp, inpf, xpad, wproj, woff, wmask, wfc1, wfc2,
                                  wfr, dww, dwb, ydwb, psum, psq);
    k_bnstats<<<128, 256, 0, stream>>>(psum, psq, gamma, beta, scs, shs);
    k_bp<<<2560, 256, 0, stream>>>(ydwb, scs, shs, x1f, inpf, wproj_f, bproj, xpad);
    k_dcn<<<1024, 512, 0, stream>>>(x1f, womb_f, boff, bmask, xpad, dcnf);
    k_mlp<<<512, 512, 0, stream>>>(dcnf, wfc1_f, bfc1, wfc2_f, bfc2, out);
}